// Round 2
// baseline (210.564 us; speedup 1.0000x reference)
//
#include <hip/hip_runtime.h>
#include <stdint.h>

#define B_SZ  4096
#define HEADS 16
#define HD    64
#define M_SZ  4096
#define K_IN  1024
#define SW    72    // padded LDS row stride (f16 elems)
#define LOG2E 1.44269504088896f

typedef _Float16 f16;
typedef f16  f16x4 __attribute__((ext_vector_type(4)));
typedef f16  f16x8 __attribute__((ext_vector_type(8)));
typedef float f32x4 __attribute__((ext_vector_type(4)));

union U8 { uint4 u4; f16x8 h8; unsigned int ui[4]; unsigned short us[8]; };

__device__ __forceinline__ unsigned short f2h(float f) {
    _Float16 h = (_Float16)f;
    return __builtin_bit_cast(unsigned short, h);
}
__device__ __forceinline__ f16x8 ldsv8(const unsigned short* p) {
    U8 u; u.u4 = *reinterpret_cast<const uint4*>(p); return u.h8;
}

#if __has_builtin(__builtin_amdgcn_exp2f)
#define EXP2F(x) __builtin_amdgcn_exp2f(x)
#else
#define EXP2F(x) __expf((x) * 0.6931471805599453f)
#endif

// async global -> LDS: lane i's 16 B land at ldsbase + i*16
__device__ __forceinline__ void gload_lds16(const void* g, void* l) {
    __builtin_amdgcn_global_load_lds(
        (const __attribute__((address_space(1))) void*)g,
        (__attribute__((address_space(3))) void*)l, 16, 0, 0);
}

// ---------------------------------------------------------------------------
// Kernel 0: f32 -> f16 conversion of x and Wq (one pass).  [verbatim]
// ---------------------------------------------------------------------------
__global__ __launch_bounds__(256) void k_conv(const float* __restrict__ x,
                                              const float* __restrict__ Wq,
                                              unsigned short* __restrict__ xh,
                                              unsigned short* __restrict__ Wh) {
    const int b = blockIdx.x;
    const float* src;
    unsigned short* dst;
    size_t base;
    if (b < 2048) { src = x;  dst = xh; base = (size_t)b * 2048; }
    else          { src = Wq; dst = Wh; base = (size_t)(b - 2048) * 2048; }
    const size_t i = base + (size_t)threadIdx.x * 8;
    float4 f0 = reinterpret_cast<const float4*>(src + i)[0];
    float4 f1 = reinterpret_cast<const float4*>(src + i)[1];
    U8 u;
    u.us[0] = f2h(f0.x); u.us[1] = f2h(f0.y); u.us[2] = f2h(f0.z); u.us[3] = f2h(f0.w);
    u.us[4] = f2h(f1.x); u.us[5] = f2h(f1.y); u.us[6] = f2h(f1.z); u.us[7] = f2h(f1.w);
    *reinterpret_cast<uint4*>(dst + i) = u.u4;
}

// ---------------------------------------------------------------------------
// Kernel 1: normalize memories, emit NEW frag-ordered layout:
// F[h][pair(32)][msl(4)][chunk(8)][lane(64)][8]  (pair = 128 m, msl = 16-m slice)
// chunks 0..3 (= hf*2+s): QK A-frag (16x16x32) for tile hf of the pair:
//   lane l: us[j] = Mn[pair*128 + hf*64 + msl*16 + (l&15)][d = s*32 + (l>>4)*8 + j]
// chunks 4..7 (= 4+n): PV B-frag (16x16x32), K spans BOTH tiles of the pair:
//   k = (l>>4)*8 + j;  j<4 -> tileA m = msl*16 + (l>>4)*4 + j
//                      j>=4 -> tileB m = msl*16 + (l>>4)*4 + (j-4)
//   us[j] = Vn[that m][d = n*16 + (l&15)]   (tile hf writes half: us[hf*4..hf*4+3])
// QK D-regs feed PV A-operand directly: P.us = {exp(Sa[0..3]), exp(Sb[0..3])}.
// ---------------------------------------------------------------------------
__global__ __launch_bounds__(256) void k_prep_mem(const float* __restrict__ mem,
                                                  unsigned short* __restrict__ F) {
    __shared__ float part[64][4];
    __shared__ float scale[64];
    __shared__ unsigned short Tn[64 * SW];

    const int h  = blockIdx.y;
    const int tl = blockIdx.x;          // 64-m tile index 0..63
    const int m0 = tl * 64;
    const int tid = threadIdx.x;
    const int r = tid >> 2;
    const int c = tid & 3;

    const float* src = mem + ((size_t)(h * M_SZ + m0 + r)) * HD + c * 16;
    float v[16];
    float ss = 0.f;
#pragma unroll
    for (int i = 0; i < 4; i++) {
        float4 f = reinterpret_cast<const float4*>(src)[i];
        v[4*i+0] = f.x; v[4*i+1] = f.y; v[4*i+2] = f.z; v[4*i+3] = f.w;
        ss += f.x*f.x + f.y*f.y + f.z*f.z + f.w*f.w;
    }
    part[r][c] = ss;
    __syncthreads();
    if (tid < 64) {
        float s = part[tid][0] + part[tid][1] + part[tid][2] + part[tid][3];
        scale[tid] = rsqrtf(s);
    }
    __syncthreads();
    const float sc = scale[r];

    U8 a, b;
#pragma unroll
    for (int i = 0; i < 8; i++) { a.us[i] = f2h(v[i] * sc); b.us[i] = f2h(v[8 + i] * sc); }
    *reinterpret_cast<uint4*>(&Tn[r * SW + c * 16])     = a.u4;
    *reinterpret_cast<uint4*>(&Tn[r * SW + c * 16 + 8]) = b.u4;
    __syncthreads();

    const int w = tid >> 6, lane = tid & 63;
    const int l15 = lane & 15, quad = lane >> 4;
    const int p  = tl >> 1, hf = tl & 1;
    const int msl = w;                   // wave w emits m-slice w
    unsigned short* Fd = F + (((size_t)(h * 32 + p) * 4 + msl) * 8) * 512;

    // QK A-frag chunks for this tile-half
#pragma unroll
    for (int s = 0; s < 2; s++) {
        uint4 vv = *reinterpret_cast<const uint4*>(&Tn[(msl * 16 + l15) * SW + s * 32 + quad * 8]);
        *reinterpret_cast<uint4*>(Fd + (hf * 2 + s) * 512 + lane * 8) = vv;
    }
    // PV B-frag half-chunks (this tile contributes k-halves hf*4..hf*4+3)
#pragma unroll
    for (int n = 0; n < 4; n++) {
        unsigned int u0 = Tn[(msl * 16 + quad * 4 + 0) * SW + n * 16 + l15];
        unsigned int u1 = Tn[(msl * 16 + quad * 4 + 1) * SW + n * 16 + l15];
        unsigned int u2 = Tn[(msl * 16 + quad * 4 + 2) * SW + n * 16 + l15];
        unsigned int u3 = Tn[(msl * 16 + quad * 4 + 3) * SW + n * 16 + l15];
        uint2 uu; uu.x = u0 | (u1 << 16); uu.y = u2 | (u3 << 16);
        *reinterpret_cast<uint2*>(Fd + (4 + n) * 512 + lane * 8 + hf * 4) = uu;
    }
}

// ---------------------------------------------------------------------------
// Kernel 2: q = xh @ Wh^T (f16 MFMA, 128x64 tile = one head), fused L2 norm,
// prescaled by log2(e). grid (32, 16) = 512 blocks -> 2 blocks/CU. [verbatim]
// ---------------------------------------------------------------------------
__global__ __launch_bounds__(256, 2) void k_qproj(const unsigned short* __restrict__ xh,
                                                  const unsigned short* __restrict__ Wh,
                                                  unsigned short* __restrict__ qn) {
    __shared__ unsigned short As[128 * SW];
    __shared__ unsigned short Bs[64 * SW];

    const int b0 = blockIdx.x * 128;
    const int n0 = blockIdx.y * 64;     // == h*64
    const int t = threadIdx.x;
    const int w = t >> 6, lane = t & 63;
    const int l15 = lane & 15, quad = lane >> 4;

    f32x4 acc[2][4] = {};

    for (int kb = 0; kb < K_IN; kb += 64) {
        __syncthreads();
        {
            const unsigned short* px = xh + (size_t)(b0 + (t >> 1)) * K_IN + kb + (t & 1) * 32;
            const unsigned short* pw = Wh + (size_t)(n0 + (t >> 2)) * K_IN + kb + (t & 3) * 16;
            uint4 av[4];
#pragma unroll
            for (int i = 0; i < 4; i++) av[i] = reinterpret_cast<const uint4*>(px)[i];
            uint4 bv[2];
#pragma unroll
            for (int i = 0; i < 2; i++) bv[i] = reinterpret_cast<const uint4*>(pw)[i];
#pragma unroll
            for (int i = 0; i < 4; i++)
                *reinterpret_cast<uint4*>(&As[(t >> 1) * SW + (t & 1) * 32 + i * 8]) = av[i];
#pragma unroll
            for (int i = 0; i < 2; i++)
                *reinterpret_cast<uint4*>(&Bs[(t >> 2) * SW + (t & 3) * 16 + i * 8]) = bv[i];
        }
        __syncthreads();

#pragma unroll
        for (int s = 0; s < 2; s++) {
            f16x8 af[2];
#pragma unroll
            for (int qg = 0; qg < 2; qg++)
                af[qg] = ldsv8(&As[(w * 32 + qg * 16 + l15) * SW + s * 32 + quad * 8]);
#pragma unroll
            for (int g = 0; g < 4; g++) {
                f16x8 bf_ = ldsv8(&Bs[(g * 16 + l15) * SW + s * 32 + quad * 8]);
#pragma unroll
                for (int qg = 0; qg < 2; qg++)
                    acc[qg][g] = __builtin_amdgcn_mfma_f32_16x16x32_f16(af[qg], bf_, acc[qg][g], 0, 0, 0);
            }
        }
    }

    __syncthreads();
    unsigned short* Ct = As;   // 128 x SW
#pragma unroll
    for (int qg = 0; qg < 2; qg++) {
        float ssq[4];
#pragma unroll
        for (int r = 0; r < 4; r++) {
            float s = 0.f;
#pragma unroll
            for (int g = 0; g < 4; g++) s += acc[qg][g][r] * acc[qg][g][r];
            ssq[r] = s;
        }
#pragma unroll
        for (int mask = 1; mask <= 8; mask <<= 1)
#pragma unroll
            for (int r = 0; r < 4; r++) ssq[r] += __shfl_xor(ssq[r], mask, 64);
#pragma unroll
        for (int r = 0; r < 4; r++) {
            float inv = rsqrtf(ssq[r]) * LOG2E;
#pragma unroll
            for (int g = 0; g < 4; g++)
                Ct[(w * 32 + qg * 16 + quad * 4 + r) * SW + g * 16 + l15] = f2h(acc[qg][g][r] * inv);
        }
    }
    __syncthreads();

    const int row = t >> 1, half = (t & 1) * 32;
    unsigned short* dq = qn + (size_t)(b0 + row) * 1024 + n0 + half;
#pragma unroll
    for (int i = 0; i < 4; i++)
        reinterpret_cast<uint4*>(dq)[i] = *reinterpret_cast<const uint4*>(&Ct[row * SW + half + i * 8]);
}

// ---------------------------------------------------------------------------
// Kernel 3: fused attention v3 — 2-D wave split. grid 512 (128 q x 1 head),
// 512 threads = 8 waves = qh(2: 64-q half) x msl(4: 16-m slice).
// Each wave reads ONLY its m-slice from LDS (8 KB per 128-m pair) -> per-CU
// LDS traffic 4x lower than q-split; MFMA becomes the binding pipe.
// Tiles processed in PAIRS (PV K=32 spans both 16-m halves). Double-buffered
// 32 KB pair staging via global_load_lds; 1 barrier per pair.
// Epilogue: cross-wave (msl) tree-reduce of accO/lsum in LDS, then store.
// ---------------------------------------------------------------------------
__global__ __launch_bounds__(512, 2) void k_attn(const unsigned short* __restrict__ qn,
                                                 const unsigned short* __restrict__ F,
                                                 float* __restrict__ out) {
    __shared__ __align__(16) unsigned char smem[65536];   // staging / reduce union
    unsigned short* bufh = reinterpret_cast<unsigned short*>(smem);

    const int b = blockIdx.x;
    const int h  = 2 * (b & 7) + (b >> 8);    // XCD k serves heads {2k, 2k+1}
    const int b0 = ((b >> 3) & 31) * 128;
    const int t = threadIdx.x;
    const int w = t >> 6, lane = t & 63;
    const int l15 = lane & 15, quad = lane >> 4;
    const int qh = w >> 2, msl = w & 3;

    // Q as B-operand of 16x16x32: lane holds Q[q=l15][d = s*32 + quad*8 + j]
    // wave covers q rows b0 + qh*64 .. +63 (4 q-groups)
    f16x8 qf[4][2];
#pragma unroll
    for (int qg = 0; qg < 4; qg++)
#pragma unroll
        for (int s = 0; s < 2; s++) {
            U8 u;
            u.u4 = *reinterpret_cast<const uint4*>(
                qn + (size_t)(b0 + qh * 64 + qg * 16 + l15) * 1024 + h * 64 + s * 32 + quad * 8);
            qf[qg][s] = u.h8;
        }

    const unsigned short* Fh = F + (size_t)h * 32 * 16384;   // 32 pairs x 16K f16

    f32x4 accO[4][4] = {};
    float lsum[4] = {0.f, 0.f, 0.f, 0.f};

    // ---- stage pair 0 (all 8 waves cooperate: 32 chunks of 1 KB) ----
#pragma unroll
    for (int i = 0; i < 4; i++) {
        const int cg = w * 4 + i;
        gload_lds16(Fh + cg * 512 + lane * 8, bufh + cg * 512);
    }

    for (int p = 0; p < 32; ++p) {
        __syncthreads();    // pair p staged (implicit vmcnt drain); buf[(p+1)&1] free
        const unsigned short* lb = bufh + (p & 1) * 16384;
        if (p + 1 < 32) {
            const unsigned short* gs = Fh + (size_t)(p + 1) * 16384;
            unsigned short* ls = bufh + ((p + 1) & 1) * 16384;
#pragma unroll
            for (int i = 0; i < 4; i++) {
                const int cg = w * 4 + i;
                gload_lds16(gs + cg * 512 + lane * 8, ls + cg * 512);
            }
        }
        const unsigned short* mb = lb + msl * 4096;   // this wave's m-slice
        f16x8 a0 = ldsv8(mb + 0 * 512 + lane * 8);    // tileA, s=0
        f16x8 a1 = ldsv8(mb + 1 * 512 + lane * 8);    // tileA, s=1
        f16x8 c0 = ldsv8(mb + 2 * 512 + lane * 8);    // tileB, s=0
        f16x8 c1 = ldsv8(mb + 3 * 512 + lane * 8);    // tileB, s=1
        f16x8 vf[4];
#pragma unroll
        for (int n = 0; n < 4; n++) vf[n] = ldsv8(mb + (4 + n) * 512 + lane * 8);

#pragma unroll
        for (int qg = 0; qg < 4; qg++) {
            f32x4 Sa = {0.f,0.f,0.f,0.f}, Sb = {0.f,0.f,0.f,0.f};
            Sa = __builtin_amdgcn_mfma_f32_16x16x32_f16(a0, qf[qg][0], Sa, 0, 0, 0);
            Sa = __builtin_amdgcn_mfma_f32_16x16x32_f16(a1, qf[qg][1], Sa, 0, 0, 0);
            Sb = __builtin_amdgcn_mfma_f32_16x16x32_f16(c0, qf[qg][0], Sb, 0, 0, 0);
            Sb = __builtin_amdgcn_mfma_f32_16x16x32_f16(c1, qf[qg][1], Sb, 0, 0, 0);
            float p0 = EXP2F(Sa[0]), p1 = EXP2F(Sa[1]), p2 = EXP2F(Sa[2]), p3 = EXP2F(Sa[3]);
            float p4 = EXP2F(Sb[0]), p5 = EXP2F(Sb[1]), p6 = EXP2F(Sb[2]), p7 = EXP2F(Sb[3]);
            lsum[qg] += ((p0 + p1) + (p2 + p3)) + ((p4 + p5) + (p6 + p7));
            U8 pu;
#if __has_builtin(__builtin_amdgcn_cvt_pkrtz)
            pu.ui[0] = __builtin_bit_cast(unsigned int, __builtin_amdgcn_cvt_pkrtz(p0, p1));
            pu.ui[1] = __builtin_bit_cast(unsigned int, __builtin_amdgcn_cvt_pkrtz(p2, p3));
            pu.ui[2] = __builtin_bit_cast(unsigned int, __builtin_amdgcn_cvt_pkrtz(p4, p5));
            pu.ui[3] = __builtin_bit_cast(unsigned int, __builtin_amdgcn_cvt_pkrtz(p6, p7));
#else
            pu.us[0]=f2h(p0); pu.us[1]=f2h(p1); pu.us[2]=f2h(p2); pu.us[3]=f2h(p3);
            pu.us[4]=f2h(p4); pu.us[5]=f2h(p5); pu.us[6]=f2h(p6); pu.us[7]=f2h(p7);
#endif
            const f16x8 puh = pu.h8;
#pragma unroll
            for (int n = 0; n < 4; n++)
                accO[qg][n] = __builtin_amdgcn_mfma_f32_16x16x32_f16(puh, vf[n], accO[qg][n], 0, 0, 0);
        }
    }

    // ---- cross-wave reduce over msl, normalize, store ----
    __syncthreads();                                   // done with staging LDS
    float* R  = reinterpret_cast<float*>(smem);        // [2][64][72] f32 (36864 B)
    float* Ls = reinterpret_cast<float*>(smem) + 2 * 64 * 72;   // [8][64] f32

#pragma unroll
    for (int qg = 0; qg < 4; qg++) {
        lsum[qg] += __shfl_xor(lsum[qg], 16, 64);
        lsum[qg] += __shfl_xor(lsum[qg], 32, 64);
    }
    if (quad == 0) {
#pragma unroll
        for (int qg = 0; qg < 4; qg++) Ls[w * 64 + qg * 16 + l15] = lsum[qg];
    }
    float* Rq = R + qh * (64 * 72);
    for (int rnd = 0; rnd < 4; ++rnd) {
        if (msl == rnd) {
            if (rnd == 0) {
#pragma unroll
                for (int qg = 0; qg < 4; qg++)
#pragma unroll
                    for (int n = 0; n < 4; n++)
#pragma unroll
                        for (int r = 0; r < 4; r++)
                            Rq[(qg * 16 + quad * 4 + r) * 72 + n * 16 + l15] = accO[qg][n][r];
            } else {
#pragma unroll
                for (int qg = 0; qg < 4; qg++)
#pragma unroll
                    for (int n = 0; n < 4; n++)
#pragma unroll
                        for (int r = 0; r < 4; r++)
                            Rq[(qg * 16 + quad * 4 + r) * 72 + n * 16 + l15] += accO[qg][n][r];
            }
        }
        __syncthreads();
    }

    {
        const int q   = t >> 2;        // 0..127
        const int dq  = t & 3;         // 16-d chunk
        const int qh2 = q >> 6, ql = q & 63;
        const float lt = Ls[(qh2 * 4 + 0) * 64 + ql] + Ls[(qh2 * 4 + 1) * 64 + ql]
                       + Ls[(qh2 * 4 + 2) * 64 + ql] + Ls[(qh2 * 4 + 3) * 64 + ql];
        const float inv = 8.0f / lt;   // sqrt(HEAD_DIM) = 8
        const float* Rr = R + qh2 * (64 * 72) + ql * 72 + dq * 16;
        float* po = out + (size_t)(b0 + q) * 1024 + h * 64 + dq * 16;
#pragma unroll
        for (int j = 0; j < 4; j++) {
            f32x4 v = *reinterpret_cast<const f32x4*>(Rr + j * 4);
            v = v * inv;
            *reinterpret_cast<f32x4*>(po + j * 4) = v;
        }
    }
}

// ---------------------------------------------------------------------------
extern "C" void kernel_launch(void* const* d_in, const int* in_sizes, int n_in,
                              void* d_out, int out_size, void* d_ws, size_t ws_size,
                              hipStream_t stream) {
    (void)in_sizes; (void)n_in; (void)out_size; (void)ws_size;
    const float* x   = (const float*)d_in[0];
    const float* Wq  = (const float*)d_in[1];
    const float* mem = (const float*)d_in[2];
    float* out = (float*)d_out;

    unsigned short* qn = (unsigned short*)d_ws;                 // 8 MB
    unsigned short* F  = qn + (size_t)B_SZ * 1024;              // 16 MB (frag-ordered)
    unsigned short* xh = F  + (size_t)HEADS * 64 * 16 * 512;    // 8 MB
    unsigned short* Wh = xh + (size_t)B_SZ * K_IN;              // 2 MB   (total 34 MB)

    k_conv    <<<2560, 256, 0, stream>>>(x, Wq, xh, Wh);
    k_prep_mem<<<dim3(64, 16), 256, 0, stream>>>(mem, F);
    k_qproj   <<<dim3(32, 16), 256, 0, stream>>>(xh, Wh, qn);
    k_attn    <<<512, 512, 0, stream>>>(qn, F, out);
}

// Round 3
// 189.875 us; speedup vs baseline: 1.1090x; 1.1090x over previous
//
#include <hip/hip_runtime.h>
#include <stdint.h>

#define B_SZ  4096
#define HEADS 16
#define HD    64
#define M_SZ  4096
#define K_IN  1024
#define SW    72    // padded LDS row stride (f16 elems)
#define LOG2E 1.44269504088896f

typedef _Float16 f16;
typedef f16  f16x4 __attribute__((ext_vector_type(4)));
typedef f16  f16x8 __attribute__((ext_vector_type(8)));
typedef float f32x4 __attribute__((ext_vector_type(4)));

union U8 { uint4 u4; f16x8 h8; unsigned int ui[4]; unsigned short us[8]; };

__device__ __forceinline__ unsigned short f2h(float f) {
    _Float16 h = (_Float16)f;
    return __builtin_bit_cast(unsigned short, h);
}
__device__ __forceinline__ f16x8 ldsv8(const unsigned short* p) {
    U8 u; u.u4 = *reinterpret_cast<const uint4*>(p); return u.h8;
}

#if __has_builtin(__builtin_amdgcn_exp2f)
#define EXP2F(x) __builtin_amdgcn_exp2f(x)
#else
#define EXP2F(x) __expf((x) * 0.6931471805599453f)
#endif

// async global -> LDS: lane i's 16 B land at ldsbase + i*16
__device__ __forceinline__ void gload_lds16(const void* g, void* l) {
    __builtin_amdgcn_global_load_lds(
        (const __attribute__((address_space(1))) void*)g,
        (__attribute__((address_space(3))) void*)l, 16, 0, 0);
}

// ---------------------------------------------------------------------------
// Kernel 0: f32 -> f16 conversion of x and Wq (one pass).  [round-0 verbatim]
// ---------------------------------------------------------------------------
__global__ __launch_bounds__(256) void k_conv(const float* __restrict__ x,
                                              const float* __restrict__ Wq,
                                              unsigned short* __restrict__ xh,
                                              unsigned short* __restrict__ Wh) {
    const int b = blockIdx.x;
    const float* src;
    unsigned short* dst;
    size_t base;
    if (b < 2048) { src = x;  dst = xh; base = (size_t)b * 2048; }
    else          { src = Wq; dst = Wh; base = (size_t)(b - 2048) * 2048; }
    const size_t i = base + (size_t)threadIdx.x * 8;
    float4 f0 = reinterpret_cast<const float4*>(src + i)[0];
    float4 f1 = reinterpret_cast<const float4*>(src + i)[1];
    U8 u;
    u.us[0] = f2h(f0.x); u.us[1] = f2h(f0.y); u.us[2] = f2h(f0.z); u.us[3] = f2h(f0.w);
    u.us[4] = f2h(f1.x); u.us[5] = f2h(f1.y); u.us[6] = f2h(f1.z); u.us[7] = f2h(f1.w);
    *reinterpret_cast<uint4*>(dst + i) = u.u4;
}

// ---------------------------------------------------------------------------
// Kernel 1: normalize memories, emit fragment-ordered F[h][tile64][chunk16][lane][8]
// chunks 0..7  (gs=g*2+s): QK A-frag (16x16x32), PERMUTED m:
//   elem = Mn[m_phys(g, lane&15)][d = s*32 + (lane>>4)*8 + j]
//   m_phys(g,r) = 32*(g>>1) + (r>>2)*8 + 4*(g&1) + (r&3)
// chunks 8..15 (c2=p*4+n): PV B-frag (16x16x32), physical m:
//   elem = Mn[32*p + (lane>>4)*8 + j][d = n*16 + (lane&15)]
// After QK+exp, lane's regs {g=2p,r0..3; g=2p+1,r0..3} are exactly the PV A-frag.
// [round-0 verbatim]
// ---------------------------------------------------------------------------
__global__ __launch_bounds__(256) void k_prep_mem(const float* __restrict__ mem,
                                                  unsigned short* __restrict__ F) {
    __shared__ float part[64][4];
    __shared__ float scale[64];
    __shared__ unsigned short Tn[64 * SW];

    const int h  = blockIdx.y;
    const int tl = blockIdx.x;
    const int m0 = tl * 64;
    const int tid = threadIdx.x;
    const int r = tid >> 2;
    const int c = tid & 3;

    const float* src = mem + ((size_t)(h * M_SZ + m0 + r)) * HD + c * 16;
    float v[16];
    float ss = 0.f;
#pragma unroll
    for (int i = 0; i < 4; i++) {
        float4 f = reinterpret_cast<const float4*>(src)[i];
        v[4*i+0] = f.x; v[4*i+1] = f.y; v[4*i+2] = f.z; v[4*i+3] = f.w;
        ss += f.x*f.x + f.y*f.y + f.z*f.z + f.w*f.w;
    }
    part[r][c] = ss;
    __syncthreads();
    if (tid < 64) {
        float s = part[tid][0] + part[tid][1] + part[tid][2] + part[tid][3];
        scale[tid] = rsqrtf(s);
    }
    __syncthreads();
    const float sc = scale[r];

    U8 a, b;
#pragma unroll
    for (int i = 0; i < 8; i++) { a.us[i] = f2h(v[i] * sc); b.us[i] = f2h(v[8 + i] * sc); }
    *reinterpret_cast<uint4*>(&Tn[r * SW + c * 16])     = a.u4;
    *reinterpret_cast<uint4*>(&Tn[r * SW + c * 16 + 8]) = b.u4;
    __syncthreads();

    const int w = tid >> 6, lane = tid & 63;
    const int l15 = lane & 15, quad = lane >> 4;
    unsigned short* Fd = F + ((size_t)(h * 64 + tl) * 16) * 512;

    // QK A-frag chunks (permuted m)
#pragma unroll
    for (int i = 0; i < 2; i++) {
        const int ch = w * 2 + i, g = ch >> 1, s = ch & 1;
        const int mp = 32 * (g >> 1) + ((l15 >> 2) * 8) + 4 * (g & 1) + (l15 & 3);
        uint4 vv = *reinterpret_cast<const uint4*>(&Tn[mp * SW + s * 32 + quad * 8]);
        *reinterpret_cast<uint4*>(Fd + ch * 512 + lane * 8) = vv;
    }
    // PV B-frag chunks (physical m)
#pragma unroll
    for (int i = 0; i < 2; i++) {
        const int c2 = w * 2 + i, p = c2 >> 2, n = c2 & 3;
        U8 u;
#pragma unroll
        for (int j = 0; j < 8; j++)
            u.us[j] = Tn[(32 * p + quad * 8 + j) * SW + n * 16 + l15];
        *reinterpret_cast<uint4*>(Fd + (8 + c2) * 512 + lane * 8) = u.u4;
    }
}

// ---------------------------------------------------------------------------
// Kernel 2: q = xh @ Wh^T (f16 MFMA, 128x64 tile = one head), fused L2 norm,
// prescaled by log2(e). grid (32, 16) = 512 blocks -> 2 blocks/CU. [verbatim]
// ---------------------------------------------------------------------------
__global__ __launch_bounds__(256, 2) void k_qproj(const unsigned short* __restrict__ xh,
                                                  const unsigned short* __restrict__ Wh,
                                                  unsigned short* __restrict__ qn) {
    __shared__ unsigned short As[128 * SW];
    __shared__ unsigned short Bs[64 * SW];

    const int b0 = blockIdx.x * 128;
    const int n0 = blockIdx.y * 64;     // == h*64
    const int t = threadIdx.x;
    const int w = t >> 6, lane = t & 63;
    const int l15 = lane & 15, quad = lane >> 4;

    f32x4 acc[2][4] = {};

    for (int kb = 0; kb < K_IN; kb += 64) {
        __syncthreads();
        {
            const unsigned short* px = xh + (size_t)(b0 + (t >> 1)) * K_IN + kb + (t & 1) * 32;
            const unsigned short* pw = Wh + (size_t)(n0 + (t >> 2)) * K_IN + kb + (t & 3) * 16;
            uint4 av[4];
#pragma unroll
            for (int i = 0; i < 4; i++) av[i] = reinterpret_cast<const uint4*>(px)[i];
            uint4 bv[2];
#pragma unroll
            for (int i = 0; i < 2; i++) bv[i] = reinterpret_cast<const uint4*>(pw)[i];
#pragma unroll
            for (int i = 0; i < 4; i++)
                *reinterpret_cast<uint4*>(&As[(t >> 1) * SW + (t & 1) * 32 + i * 8]) = av[i];
#pragma unroll
            for (int i = 0; i < 2; i++)
                *reinterpret_cast<uint4*>(&Bs[(t >> 2) * SW + (t & 3) * 16 + i * 8]) = bv[i];
        }
        __syncthreads();

#pragma unroll
        for (int s = 0; s < 2; s++) {
            f16x8 af[2];
#pragma unroll
            for (int qg = 0; qg < 2; qg++)
                af[qg] = ldsv8(&As[(w * 32 + qg * 16 + l15) * SW + s * 32 + quad * 8]);
#pragma unroll
            for (int g = 0; g < 4; g++) {
                f16x8 bf_ = ldsv8(&Bs[(g * 16 + l15) * SW + s * 32 + quad * 8]);
#pragma unroll
                for (int qg = 0; qg < 2; qg++)
                    acc[qg][g] = __builtin_amdgcn_mfma_f32_16x16x32_f16(af[qg], bf_, acc[qg][g], 0, 0, 0);
            }
        }
    }

    __syncthreads();
    unsigned short* Ct = As;   // 128 x SW
#pragma unroll
    for (int qg = 0; qg < 2; qg++) {
        float ssq[4];
#pragma unroll
        for (int r = 0; r < 4; r++) {
            float s = 0.f;
#pragma unroll
            for (int g = 0; g < 4; g++) s += acc[qg][g][r] * acc[qg][g][r];
            ssq[r] = s;
        }
#pragma unroll
        for (int mask = 1; mask <= 8; mask <<= 1)
#pragma unroll
            for (int r = 0; r < 4; r++) ssq[r] += __shfl_xor(ssq[r], mask, 64);
#pragma unroll
        for (int r = 0; r < 4; r++) {
            float inv = rsqrtf(ssq[r]) * LOG2E;
#pragma unroll
            for (int g = 0; g < 4; g++)
                Ct[(w * 32 + qg * 16 + quad * 4 + r) * SW + g * 16 + l15] = f2h(acc[qg][g][r] * inv);
        }
    }
    __syncthreads();

    const int row = t >> 1, half = (t & 1) * 32;
    unsigned short* dq = qn + (size_t)(b0 + row) * 1024 + n0 + half;
#pragma unroll
    for (int i = 0; i < 4; i++)
        reinterpret_cast<uint4*>(dq)[i] = *reinterpret_cast<const uint4*>(&Ct[row * SW + half + i * 8]);
}

// ---------------------------------------------------------------------------
// Kernel 3: fused attention v4 — round-0 pipeline, qg=4 (wave owns 64 q).
// grid 256 (256 q x 1 head), 4 waves/block = 1 block/CU, 1 wave/SIMD.
// LDS per CU per tile: 4 waves x 16 KB = 64 KB (half of round-0) -> LDS term
// (~770 cyc) drops below MFMA term (~1240 cyc/SIMD). Pipeline unchanged:
// PV(tl) MFMAs interleave with QK(tl+1) MFMAs; exp deferred one group;
// pu/bw register double-buffered. ~300 VGPR is fine at 1 wave/SIMD (<450).
// ---------------------------------------------------------------------------
__global__ __launch_bounds__(256, 1) void k_attn(const unsigned short* __restrict__ qn,
                                                 const unsigned short* __restrict__ F,
                                                 float* __restrict__ out) {
    __shared__ unsigned short buf[2][8192];   // 2 x 16 KB

    const int b = blockIdx.x;                 // 256 blocks
    const int h  = 2 * (b & 7) + (b >> 7);    // XCD k serves heads {2k, 2k+1}
    const int b0 = ((b >> 3) & 15) * 256;
    const int t = threadIdx.x;
    const int w = t >> 6, lane = t & 63;
    const int l15 = lane & 15, quad = lane >> 4;

    // Q as B-operand of 16x16x32: lane holds Q[q=l15][d = s*32 + quad*8 + j]
    // wave w owns q rows b0 + w*64 .. +63 (4 q-groups of 16)
    f16x8 qf[4][2];
#pragma unroll
    for (int qg = 0; qg < 4; qg++)
#pragma unroll
        for (int s = 0; s < 2; s++) {
            U8 u;
            u.u4 = *reinterpret_cast<const uint4*>(
                qn + (size_t)(b0 + w * 64 + qg * 16 + l15) * 1024 + h * 64 + s * 32 + quad * 8);
            qf[qg][s] = u.h8;
        }

    const unsigned short* Fh = F + (size_t)h * 64 * 8192;

    f32x4 accO[4][4] = {};
    float lsum[4] = {0.f, 0.f, 0.f, 0.f};

    // pipeline register state (double-buffered)
    f16x8 puA[4][2], puB[4][2];   // P A-frags [qg][p]
    f16x8 bwA[8],   bwB[8];       // V B-frags [p*4+n]

    // ---- prologue: stage tile 0, compute pu(0)/bw(0) into set A ----
#pragma unroll
    for (int i = 0; i < 4; i++) {
        const int ch = w * 4 + i;
        gload_lds16(Fh + ch * 512 + lane * 8, &buf[0][ch * 512]);
    }
    __syncthreads();
    {
        f16x8 am[8];
#pragma unroll
        for (int ch = 0; ch < 8; ch++) am[ch] = ldsv8(&buf[0][ch * 512 + lane * 8]);
#pragma unroll
        for (int ch = 0; ch < 8; ch++) bwA[ch] = ldsv8(&buf[0][(8 + ch) * 512 + lane * 8]);
        // stage tile 1 (buf[1]) while computing QK(0)
#pragma unroll
        for (int i = 0; i < 4; i++) {
            const int ch = w * 4 + i;
            gload_lds16(Fh + 8192 + ch * 512 + lane * 8, &buf[1][ch * 512]);
        }
#pragma unroll
        for (int g8 = 0; g8 < 8; g8++) {
            const int qg = g8 >> 1, p = g8 & 1;
            f32x4 t0 = {0.f,0.f,0.f,0.f}, t1 = {0.f,0.f,0.f,0.f};
            t0 = __builtin_amdgcn_mfma_f32_16x16x32_f16(am[4*p+0], qf[qg][0], t0, 0, 0, 0);
            t0 = __builtin_amdgcn_mfma_f32_16x16x32_f16(am[4*p+1], qf[qg][1], t0, 0, 0, 0);
            t1 = __builtin_amdgcn_mfma_f32_16x16x32_f16(am[4*p+2], qf[qg][0], t1, 0, 0, 0);
            t1 = __builtin_amdgcn_mfma_f32_16x16x32_f16(am[4*p+3], qf[qg][1], t1, 0, 0, 0);
            float p0 = EXP2F(t0[0]), p1 = EXP2F(t0[1]), p2 = EXP2F(t0[2]), p3 = EXP2F(t0[3]);
            float p4 = EXP2F(t1[0]), p5 = EXP2F(t1[1]), p6 = EXP2F(t1[2]), p7 = EXP2F(t1[3]);
            lsum[qg] += ((p0 + p1) + (p2 + p3)) + ((p4 + p5) + (p6 + p7));
            U8 pu;
#if __has_builtin(__builtin_amdgcn_cvt_pkrtz)
            pu.ui[0] = __builtin_bit_cast(unsigned int, __builtin_amdgcn_cvt_pkrtz(p0, p1));
            pu.ui[1] = __builtin_bit_cast(unsigned int, __builtin_amdgcn_cvt_pkrtz(p2, p3));
            pu.ui[2] = __builtin_bit_cast(unsigned int, __builtin_amdgcn_cvt_pkrtz(p4, p5));
            pu.ui[3] = __builtin_bit_cast(unsigned int, __builtin_amdgcn_cvt_pkrtz(p6, p7));
#else
            pu.us[0]=f2h(p0); pu.us[1]=f2h(p1); pu.us[2]=f2h(p2); pu.us[3]=f2h(p3);
            pu.us[4]=f2h(p4); pu.us[5]=f2h(p5); pu.us[6]=f2h(p6); pu.us[7]=f2h(p7);
#endif
            puA[qg][p] = pu.h8;
        }
    }

    // ---- pipelined body: PV(tl) || QK(tl+1) ----
    auto body = [&](int tl, f16x8 (&puC)[4][2], f16x8 (&bwC)[8],
                            f16x8 (&puN)[4][2], f16x8 (&bwN)[8]) {
        __syncthreads();   // tile tl+1 staged; all waves done ds-reading buf[tl&1]
        const unsigned short* lb = buf[(tl + 1) & 1];
        f16x8 amn[8];
#pragma unroll
        for (int ch = 0; ch < 8; ch++) amn[ch] = ldsv8(&lb[ch * 512 + lane * 8]);
#pragma unroll
        for (int ch = 0; ch < 8; ch++) bwN[ch] = ldsv8(&lb[(8 + ch) * 512 + lane * 8]);
        if (tl + 2 < 64) {   // overwrite buf[tl&1] (tile tl frags already in regs)
            const unsigned short* gsrc = Fh + (size_t)(tl + 2) * 8192;
#pragma unroll
            for (int i = 0; i < 4; i++) {
                const int ch = w * 4 + i;
                gload_lds16(gsrc + ch * 512 + lane * 8, &buf[tl & 1][ch * 512]);
            }
        }

        f32x4 sa[8], sb[8];
        auto expPack = [&](int g8) {
            const int qg = g8 >> 1, p = g8 & 1;
            float p0 = EXP2F(sa[g8][0]), p1 = EXP2F(sa[g8][1]), p2 = EXP2F(sa[g8][2]), p3 = EXP2F(sa[g8][3]);
            float p4 = EXP2F(sb[g8][0]), p5 = EXP2F(sb[g8][1]), p6 = EXP2F(sb[g8][2]), p7 = EXP2F(sb[g8][3]);
            lsum[qg] += ((p0 + p1) + (p2 + p3)) + ((p4 + p5) + (p6 + p7));
            U8 pu;
#if __has_builtin(__builtin_amdgcn_cvt_pkrtz)
            pu.ui[0] = __builtin_bit_cast(unsigned int, __builtin_amdgcn_cvt_pkrtz(p0, p1));
            pu.ui[1] = __builtin_bit_cast(unsigned int, __builtin_amdgcn_cvt_pkrtz(p2, p3));
            pu.ui[2] = __builtin_bit_cast(unsigned int, __builtin_amdgcn_cvt_pkrtz(p4, p5));
            pu.ui[3] = __builtin_bit_cast(unsigned int, __builtin_amdgcn_cvt_pkrtz(p6, p7));
#else
            pu.us[0]=f2h(p0); pu.us[1]=f2h(p1); pu.us[2]=f2h(p2); pu.us[3]=f2h(p3);
            pu.us[4]=f2h(p4); pu.us[5]=f2h(p5); pu.us[6]=f2h(p6); pu.us[7]=f2h(p7);
#endif
            puN[qg][p] = pu.h8;
        };

#pragma unroll
        for (int g8 = 0; g8 < 8; g8++) {
            const int qg = g8 >> 1, p = g8 & 1;
            // QK group g8 of tile tl+1
            f32x4 t0 = {0.f,0.f,0.f,0.f}, t1 = {0.f,0.f,0.f,0.f};
            t0 = __builtin_amdgcn_mfma_f32_16x16x32_f16(amn[4*p+0], qf[qg][0], t0, 0, 0, 0);
            t0 = __builtin_amdgcn_mfma_f32_16x16x32_f16(amn[4*p+1], qf[qg][1], t0, 0, 0, 0);
            t1 = __builtin_amdgcn_mfma_f32_16x16x32_f16(amn[4*p+2], qf[qg][0], t1, 0, 0, 0);
            t1 = __builtin_amdgcn_mfma_f32_16x16x32_f16(amn[4*p+3], qf[qg][1], t1, 0, 0, 0);
            sa[g8] = t0; sb[g8] = t1;
            // PV group g8 of tile tl (independent of the QK above)
#pragma unroll
            for (int n = 0; n < 4; n++)
                accO[qg][n] = __builtin_amdgcn_mfma_f32_16x16x32_f16(puC[qg][p], bwC[p * 4 + n], accO[qg][n], 0, 0, 0);
            // exp of the PREVIOUS group (its QK results are long since ready)
            if (g8 >= 1) expPack(g8 - 1);
        }
        expPack(7);
    };

    for (int tt = 0; tt < 31; ++tt) {
        body(2 * tt,     puA, bwA, puB, bwB);
        body(2 * tt + 1, puB, bwB, puA, bwA);
    }
    body(62, puA, bwA, puB, bwB);

    // ---- epilogue: PV(63) from register set B, then normalize + store ----
#pragma unroll
    for (int g8 = 0; g8 < 8; g8++) {
        const int qg = g8 >> 1, p = g8 & 1;
#pragma unroll
        for (int n = 0; n < 4; n++)
            accO[qg][n] = __builtin_amdgcn_mfma_f32_16x16x32_f16(puB[qg][p], bwB[p * 4 + n], accO[qg][n], 0, 0, 0);
    }

#pragma unroll
    for (int qg = 0; qg < 4; qg++) {
        float s = lsum[qg];
        s += __shfl_xor(s, 16, 64);
        s += __shfl_xor(s, 32, 64);
        float inv = 8.0f / s;    // sqrt(HEAD_DIM) = 8
#pragma unroll
        for (int r = 0; r < 4; r++) {
            float iv = __shfl(inv, quad * 4 + r, 64);
            float* po = out + (size_t)(b0 + w * 64 + qg * 16 + quad * 4 + r) * 1024 + h * 64;
#pragma unroll
            for (int n = 0; n < 4; n++)
                po[n * 16 + l15] = accO[qg][n][r] * iv;
        }
    }
}

// ---------------------------------------------------------------------------
extern "C" void kernel_launch(void* const* d_in, const int* in_sizes, int n_in,
                              void* d_out, int out_size, void* d_ws, size_t ws_size,
                              hipStream_t stream) {
    (void)in_sizes; (void)n_in; (void)out_size; (void)ws_size;
    const float* x   = (const float*)d_in[0];
    const float* Wq  = (const float*)d_in[1];
    const float* mem = (const float*)d_in[2];
    float* out = (float*)d_out;

    unsigned short* qn = (unsigned short*)d_ws;                 // 8 MB
    unsigned short* F  = qn + (size_t)B_SZ * 1024;              // 16 MB (frag-ordered)
    unsigned short* xh = F  + (size_t)HEADS * 64 * 16 * 512;    // 8 MB
    unsigned short* Wh = xh + (size_t)B_SZ * K_IN;              // 2 MB   (total 34 MB)

    k_conv    <<<2560, 256, 0, stream>>>(x, Wq, xh, Wh);
    k_prep_mem<<<dim3(64, 16), 256, 0, stream>>>(mem, F);
    k_qproj   <<<dim3(32, 16), 256, 0, stream>>>(xh, Wh, qn);
    k_attn    <<<256, 256, 0, stream>>>(qn, F, out);
}

// Round 4
// 180.413 us; speedup vs baseline: 1.1671x; 1.0524x over previous
//
#include <hip/hip_runtime.h>
#include <stdint.h>

#define B_SZ  4096
#define HEADS 16
#define HD    64
#define M_SZ  4096
#define K_IN  1024
#define SW    72    // padded LDS row stride (f16 elems)
#define LOG2E 1.44269504088896f

typedef _Float16 f16;
typedef f16  f16x4 __attribute__((ext_vector_type(4)));
typedef f16  f16x8 __attribute__((ext_vector_type(8)));
typedef float f32x4 __attribute__((ext_vector_type(4)));

union U8 { uint4 u4; f16x8 h8; unsigned int ui[4]; unsigned short us[8]; };

__device__ __forceinline__ unsigned short f2h(float f) {
    _Float16 h = (_Float16)f;
    return __builtin_bit_cast(unsigned short, h);
}
__device__ __forceinline__ f16x8 ldsv8(const unsigned short* p) {
    U8 u; u.u4 = *reinterpret_cast<const uint4*>(p); return u.h8;
}
__device__ __forceinline__ f16x8 gldv8(const unsigned short* p) {
    U8 u; u.u4 = *reinterpret_cast<const uint4*>(p); return u.h8;
}

#if __has_builtin(__builtin_amdgcn_exp2f)
#define EXP2F(x) __builtin_amdgcn_exp2f(x)
#else
#define EXP2F(x) __expf((x) * 0.6931471805599453f)
#endif

// async global -> LDS: lane i's 16 B land at ldsbase + i*16
__device__ __forceinline__ void gload_lds16(const void* g, void* l) {
    __builtin_amdgcn_global_load_lds(
        (const __attribute__((address_space(1))) void*)g,
        (__attribute__((address_space(3))) void*)l, 16, 0, 0);
}

// ---------------------------------------------------------------------------
// Kernel 0: f32 -> f16 conversion of x and Wq (one pass).  [round-0 verbatim]
// ---------------------------------------------------------------------------
__global__ __launch_bounds__(256) void k_conv(const float* __restrict__ x,
                                              const float* __restrict__ Wq,
                                              unsigned short* __restrict__ xh,
                                              unsigned short* __restrict__ Wh) {
    const int b = blockIdx.x;
    const float* src;
    unsigned short* dst;
    size_t base;
    if (b < 2048) { src = x;  dst = xh; base = (size_t)b * 2048; }
    else          { src = Wq; dst = Wh; base = (size_t)(b - 2048) * 2048; }
    const size_t i = base + (size_t)threadIdx.x * 8;
    float4 f0 = reinterpret_cast<const float4*>(src + i)[0];
    float4 f1 = reinterpret_cast<const float4*>(src + i)[1];
    U8 u;
    u.us[0] = f2h(f0.x); u.us[1] = f2h(f0.y); u.us[2] = f2h(f0.z); u.us[3] = f2h(f0.w);
    u.us[4] = f2h(f1.x); u.us[5] = f2h(f1.y); u.us[6] = f2h(f1.z); u.us[7] = f2h(f1.w);
    *reinterpret_cast<uint4*>(dst + i) = u.u4;
}

// ---------------------------------------------------------------------------
// Kernel 1: normalize memories, emit fragment-ordered F[h][tile64][chunk16][lane][8]
// chunks 0..7  (gs=g*2+s): QK A-frag (16x16x32), PERMUTED m:
//   elem = Mn[m_phys(g, lane&15)][d = s*32 + (lane>>4)*8 + j]
//   m_phys(g,r) = 32*(g>>1) + (r>>2)*8 + 4*(g&1) + (r&3)
// chunks 8..15 (c2=p*4+n): PV B-frag (16x16x32), physical m:
//   elem = Mn[32*p + (lane>>4)*8 + j][d = n*16 + (lane&15)]
// After QK+exp, lane's regs {g=2p,r0..3; g=2p+1,r0..3} are exactly the PV A-frag.
// [round-0 verbatim]
// ---------------------------------------------------------------------------
__global__ __launch_bounds__(256) void k_prep_mem(const float* __restrict__ mem,
                                                  unsigned short* __restrict__ F) {
    __shared__ float part[64][4];
    __shared__ float scale[64];
    __shared__ unsigned short Tn[64 * SW];

    const int h  = blockIdx.y;
    const int tl = blockIdx.x;
    const int m0 = tl * 64;
    const int tid = threadIdx.x;
    const int r = tid >> 2;
    const int c = tid & 3;

    const float* src = mem + ((size_t)(h * M_SZ + m0 + r)) * HD + c * 16;
    float v[16];
    float ss = 0.f;
#pragma unroll
    for (int i = 0; i < 4; i++) {
        float4 f = reinterpret_cast<const float4*>(src)[i];
        v[4*i+0] = f.x; v[4*i+1] = f.y; v[4*i+2] = f.z; v[4*i+3] = f.w;
        ss += f.x*f.x + f.y*f.y + f.z*f.z + f.w*f.w;
    }
    part[r][c] = ss;
    __syncthreads();
    if (tid < 64) {
        float s = part[tid][0] + part[tid][1] + part[tid][2] + part[tid][3];
        scale[tid] = rsqrtf(s);
    }
    __syncthreads();
    const float sc = scale[r];

    U8 a, b;
#pragma unroll
    for (int i = 0; i < 8; i++) { a.us[i] = f2h(v[i] * sc); b.us[i] = f2h(v[8 + i] * sc); }
    *reinterpret_cast<uint4*>(&Tn[r * SW + c * 16])     = a.u4;
    *reinterpret_cast<uint4*>(&Tn[r * SW + c * 16 + 8]) = b.u4;
    __syncthreads();

    const int w = tid >> 6, lane = tid & 63;
    const int l15 = lane & 15, quad = lane >> 4;
    unsigned short* Fd = F + ((size_t)(h * 64 + tl) * 16) * 512;

    // QK A-frag chunks (permuted m)
#pragma unroll
    for (int i = 0; i < 2; i++) {
        const int ch = w * 2 + i, g = ch >> 1, s = ch & 1;
        const int mp = 32 * (g >> 1) + ((l15 >> 2) * 8) + 4 * (g & 1) + (l15 & 3);
        uint4 vv = *reinterpret_cast<const uint4*>(&Tn[mp * SW + s * 32 + quad * 8]);
        *reinterpret_cast<uint4*>(Fd + ch * 512 + lane * 8) = vv;
    }
    // PV B-frag chunks (physical m)
#pragma unroll
    for (int i = 0; i < 2; i++) {
        const int c2 = w * 2 + i, p = c2 >> 2, n = c2 & 3;
        U8 u;
#pragma unroll
        for (int j = 0; j < 8; j++)
            u.us[j] = Tn[(32 * p + quad * 8 + j) * SW + n * 16 + l15];
        *reinterpret_cast<uint4*>(Fd + (8 + c2) * 512 + lane * 8) = u.u4;
    }
}

// ---------------------------------------------------------------------------
// Kernel 2: q = xh @ Wh^T (f16 MFMA, 128x64 tile = one head), fused L2 norm,
// prescaled by log2(e). grid (32, 16) = 512 blocks -> 2 blocks/CU. [verbatim]
// ---------------------------------------------------------------------------
__global__ __launch_bounds__(256, 2) void k_qproj(const unsigned short* __restrict__ xh,
                                                  const unsigned short* __restrict__ Wh,
                                                  unsigned short* __restrict__ qn) {
    __shared__ unsigned short As[128 * SW];
    __shared__ unsigned short Bs[64 * SW];

    const int b0 = blockIdx.x * 128;
    const int n0 = blockIdx.y * 64;     // == h*64
    const int t = threadIdx.x;
    const int w = t >> 6, lane = t & 63;
    const int l15 = lane & 15, quad = lane >> 4;

    f32x4 acc[2][4] = {};

    for (int kb = 0; kb < K_IN; kb += 64) {
        __syncthreads();
        {
            const unsigned short* px = xh + (size_t)(b0 + (t >> 1)) * K_IN + kb + (t & 1) * 32;
            const unsigned short* pw = Wh + (size_t)(n0 + (t >> 2)) * K_IN + kb + (t & 3) * 16;
            uint4 av[4];
#pragma unroll
            for (int i = 0; i < 4; i++) av[i] = reinterpret_cast<const uint4*>(px)[i];
            uint4 bv[2];
#pragma unroll
            for (int i = 0; i < 2; i++) bv[i] = reinterpret_cast<const uint4*>(pw)[i];
#pragma unroll
            for (int i = 0; i < 4; i++)
                *reinterpret_cast<uint4*>(&As[(t >> 1) * SW + (t & 1) * 32 + i * 8]) = av[i];
#pragma unroll
            for (int i = 0; i < 2; i++)
                *reinterpret_cast<uint4*>(&Bs[(t >> 2) * SW + (t & 3) * 16 + i * 8]) = bv[i];
        }
        __syncthreads();

#pragma unroll
        for (int s = 0; s < 2; s++) {
            f16x8 af[2];
#pragma unroll
            for (int qg = 0; qg < 2; qg++)
                af[qg] = ldsv8(&As[(w * 32 + qg * 16 + l15) * SW + s * 32 + quad * 8]);
#pragma unroll
            for (int g = 0; g < 4; g++) {
                f16x8 bf_ = ldsv8(&Bs[(g * 16 + l15) * SW + s * 32 + quad * 8]);
#pragma unroll
                for (int qg = 0; qg < 2; qg++)
                    acc[qg][g] = __builtin_amdgcn_mfma_f32_16x16x32_f16(af[qg], bf_, acc[qg][g], 0, 0, 0);
            }
        }
    }

    __syncthreads();
    unsigned short* Ct = As;   // 128 x SW
#pragma unroll
    for (int qg = 0; qg < 2; qg++) {
        float ssq[4];
#pragma unroll
        for (int r = 0; r < 4; r++) {
            float s = 0.f;
#pragma unroll
            for (int g = 0; g < 4; g++) s += acc[qg][g][r] * acc[qg][g][r];
            ssq[r] = s;
        }
#pragma unroll
        for (int mask = 1; mask <= 8; mask <<= 1)
#pragma unroll
            for (int r = 0; r < 4; r++) ssq[r] += __shfl_xor(ssq[r], mask, 64);
#pragma unroll
        for (int r = 0; r < 4; r++) {
            float inv = rsqrtf(ssq[r]) * LOG2E;
#pragma unroll
            for (int g = 0; g < 4; g++)
                Ct[(w * 32 + qg * 16 + quad * 4 + r) * SW + g * 16 + l15] = f2h(acc[qg][g][r] * inv);
        }
    }
    __syncthreads();

    const int row = t >> 1, half = (t & 1) * 32;
    unsigned short* dq = qn + (size_t)(b0 + row) * 1024 + n0 + half;
#pragma unroll
    for (int i = 0; i < 4; i++)
        reinterpret_cast<uint4*>(dq)[i] = *reinterpret_cast<const uint4*>(&Ct[row * SW + half + i * 8]);
}

// ---------------------------------------------------------------------------
// Kernel 3: fused attention v5 — round-0 pipeline (77 µs known-good), with
// V-frags loaded GLOBAL->VGPR (L2-resident F) instead of via LDS.
// LDS tile 16->8 KB (QK A-frags only): per-CU LDS reads halve to 64 KB/tile
// (~770 cyc < MFMA ~1240 cyc). V loads issue one full body (~1500+ cyc)
// before use; the syncthreads vmcnt drain is their natural completion fence.
// grid 512, 4 waves, qg=2, 2 blocks/CU = 2 waves/SIMD (proven overlap).
// ---------------------------------------------------------------------------
__global__ __launch_bounds__(256, 2) void k_attn(const unsigned short* __restrict__ qn,
                                                 const unsigned short* __restrict__ F,
                                                 float* __restrict__ out) {
    __shared__ unsigned short buf[2][4096];   // 2 x 8 KB (QK chunks only)

    const int b = blockIdx.x;
    const int h  = 2 * (b & 7) + (b >> 8);    // XCD k serves heads {2k, 2k+1}
    const int b0 = ((b >> 3) & 31) * 128;
    const int t = threadIdx.x;
    const int w = t >> 6, lane = t & 63;
    const int l15 = lane & 15, quad = lane >> 4;

    // Q as B-operand of 16x16x32: lane holds Q[q=l15][d = s*32 + quad*8 + j]
    f16x8 qf[2][2];
#pragma unroll
    for (int qg = 0; qg < 2; qg++)
#pragma unroll
        for (int s = 0; s < 2; s++) {
            U8 u;
            u.u4 = *reinterpret_cast<const uint4*>(
                qn + (size_t)(b0 + w * 32 + qg * 16 + l15) * 1024 + h * 64 + s * 32 + quad * 8);
            qf[qg][s] = u.h8;
        }

    const unsigned short* Fh = F + (size_t)h * 64 * 8192;

    f32x4 accO[2][4] = {};
    float lsum[2] = {0.f, 0.f};

    // pipeline register state (double-buffered)
    f16x8 puA[2][2], puB[2][2];   // P A-frags [qg][p]
    f16x8 bwA[8],   bwB[8];       // V B-frags [p*4+n]  (filled from GLOBAL)

    // ---- prologue: stage tile-0 QK chunks, V(0) from global, pu(0) -> set A ----
#pragma unroll
    for (int i = 0; i < 2; i++) {
        const int ch = w * 2 + i;
        gload_lds16(Fh + ch * 512 + lane * 8, &buf[0][ch * 512]);
    }
    __syncthreads();
    {
        f16x8 am[8];
#pragma unroll
        for (int ch = 0; ch < 8; ch++) am[ch] = ldsv8(&buf[0][ch * 512 + lane * 8]);
#pragma unroll
        for (int ch = 0; ch < 8; ch++) bwA[ch] = gldv8(Fh + (8 + ch) * 512 + lane * 8);
        // stage tile-1 QK chunks (buf[1]) while computing QK(0)
#pragma unroll
        for (int i = 0; i < 2; i++) {
            const int ch = w * 2 + i;
            gload_lds16(Fh + 8192 + ch * 512 + lane * 8, &buf[1][ch * 512]);
        }
#pragma unroll
        for (int g = 0; g < 4; g++) {
            const int qg = g >> 1, p = g & 1;
            f32x4 t0 = {0.f,0.f,0.f,0.f}, t1 = {0.f,0.f,0.f,0.f};
            t0 = __builtin_amdgcn_mfma_f32_16x16x32_f16(am[4*p+0], qf[qg][0], t0, 0, 0, 0);
            t0 = __builtin_amdgcn_mfma_f32_16x16x32_f16(am[4*p+1], qf[qg][1], t0, 0, 0, 0);
            t1 = __builtin_amdgcn_mfma_f32_16x16x32_f16(am[4*p+2], qf[qg][0], t1, 0, 0, 0);
            t1 = __builtin_amdgcn_mfma_f32_16x16x32_f16(am[4*p+3], qf[qg][1], t1, 0, 0, 0);
            float p0 = EXP2F(t0[0]), p1 = EXP2F(t0[1]), p2 = EXP2F(t0[2]), p3 = EXP2F(t0[3]);
            float p4 = EXP2F(t1[0]), p5 = EXP2F(t1[1]), p6 = EXP2F(t1[2]), p7 = EXP2F(t1[3]);
            lsum[qg] += ((p0 + p1) + (p2 + p3)) + ((p4 + p5) + (p6 + p7));
            U8 pu;
#if __has_builtin(__builtin_amdgcn_cvt_pkrtz)
            pu.ui[0] = __builtin_bit_cast(unsigned int, __builtin_amdgcn_cvt_pkrtz(p0, p1));
            pu.ui[1] = __builtin_bit_cast(unsigned int, __builtin_amdgcn_cvt_pkrtz(p2, p3));
            pu.ui[2] = __builtin_bit_cast(unsigned int, __builtin_amdgcn_cvt_pkrtz(p4, p5));
            pu.ui[3] = __builtin_bit_cast(unsigned int, __builtin_amdgcn_cvt_pkrtz(p6, p7));
#else
            pu.us[0]=f2h(p0); pu.us[1]=f2h(p1); pu.us[2]=f2h(p2); pu.us[3]=f2h(p3);
            pu.us[4]=f2h(p4); pu.us[5]=f2h(p5); pu.us[6]=f2h(p6); pu.us[7]=f2h(p7);
#endif
            puA[qg][p] = pu.h8;
        }
    }

    // ---- pipelined body: PV(tl) || QK(tl+1) ----
    auto body = [&](int tl, f16x8 (&puC)[2][2], f16x8 (&bwC)[8],
                            f16x8 (&puN)[2][2], f16x8 (&bwN)[8]) {
        __syncthreads();   // tile tl+1 QK staged; all waves done with buf[tl&1]
        const unsigned short* lb = buf[(tl + 1) & 1];
        f16x8 amn[8];
#pragma unroll
        for (int ch = 0; ch < 8; ch++) amn[ch] = ldsv8(&lb[ch * 512 + lane * 8]);
        // V(tl+1) global->reg: used one body later; L2 latency hidden
        const unsigned short* gv = Fh + (size_t)(tl + 1) * 8192;
#pragma unroll
        for (int ch = 0; ch < 8; ch++) bwN[ch] = gldv8(gv + (8 + ch) * 512 + lane * 8);
        if (tl + 2 < 64) {   // stage tile tl+2 QK chunks over buf[tl&1]
            const unsigned short* gsrc = Fh + (size_t)(tl + 2) * 8192;
#pragma unroll
            for (int i = 0; i < 2; i++) {
                const int ch = w * 2 + i;
                gload_lds16(gsrc + ch * 512 + lane * 8, &buf[tl & 1][ch * 512]);
            }
        }

        f32x4 sa[4], sb[4];
        auto expPack = [&](int g) {
            const int qg = g >> 1, p = g & 1;
            float p0 = EXP2F(sa[g][0]), p1 = EXP2F(sa[g][1]), p2 = EXP2F(sa[g][2]), p3 = EXP2F(sa[g][3]);
            float p4 = EXP2F(sb[g][0]), p5 = EXP2F(sb[g][1]), p6 = EXP2F(sb[g][2]), p7 = EXP2F(sb[g][3]);
            lsum[qg] += ((p0 + p1) + (p2 + p3)) + ((p4 + p5) + (p6 + p7));
            U8 pu;
#if __has_builtin(__builtin_amdgcn_cvt_pkrtz)
            pu.ui[0] = __builtin_bit_cast(unsigned int, __builtin_amdgcn_cvt_pkrtz(p0, p1));
            pu.ui[1] = __builtin_bit_cast(unsigned int, __builtin_amdgcn_cvt_pkrtz(p2, p3));
            pu.ui[2] = __builtin_bit_cast(unsigned int, __builtin_amdgcn_cvt_pkrtz(p4, p5));
            pu.ui[3] = __builtin_bit_cast(unsigned int, __builtin_amdgcn_cvt_pkrtz(p6, p7));
#else
            pu.us[0]=f2h(p0); pu.us[1]=f2h(p1); pu.us[2]=f2h(p2); pu.us[3]=f2h(p3);
            pu.us[4]=f2h(p4); pu.us[5]=f2h(p5); pu.us[6]=f2h(p6); pu.us[7]=f2h(p7);
#endif
            puN[qg][p] = pu.h8;
        };

#pragma unroll
        for (int g = 0; g < 4; g++) {
            const int qg = g >> 1, p = g & 1;
            // QK group g of tile tl+1
            f32x4 t0 = {0.f,0.f,0.f,0.f}, t1 = {0.f,0.f,0.f,0.f};
            t0 = __builtin_amdgcn_mfma_f32_16x16x32_f16(amn[4*p+0], qf[qg][0], t0, 0, 0, 0);
            t0 = __builtin_amdgcn_mfma_f32_16x16x32_f16(amn[4*p+1], qf[qg][1], t0, 0, 0, 0);
            t1 = __builtin_amdgcn_mfma_f32_16x16x32_f16(amn[4*p+2], qf[qg][0], t1, 0, 0, 0);
            t1 = __builtin_amdgcn_mfma_f32_16x16x32_f16(amn[4*p+3], qf[qg][1], t1, 0, 0, 0);
            sa[g] = t0; sb[g] = t1;
            // PV group g of tile tl (independent of the QK above)
#pragma unroll
            for (int n = 0; n < 4; n++)
                accO[qg][n] = __builtin_amdgcn_mfma_f32_16x16x32_f16(puC[qg][p], bwC[p * 4 + n], accO[qg][n], 0, 0, 0);
            // exp of the PREVIOUS group (its QK results are long since ready)
            if (g >= 1) expPack(g - 1);
        }
        expPack(3);
    };

    for (int tt = 0; tt < 31; ++tt) {
        body(2 * tt,     puA, bwA, puB, bwB);
        body(2 * tt + 1, puB, bwB, puA, bwA);
    }
    body(62, puA, bwA, puB, bwB);

    // ---- epilogue: PV(63) from register set B, then normalize + store ----
#pragma unroll
    for (int g = 0; g < 4; g++) {
        const int qg = g >> 1, p = g & 1;
#pragma unroll
        for (int n = 0; n < 4; n++)
            accO[qg][n] = __builtin_amdgcn_mfma_f32_16x16x32_f16(puB[qg][p], bwB[p * 4 + n], accO[qg][n], 0, 0, 0);
    }

#pragma unroll
    for (int qg = 0; qg < 2; qg++) {
        float s = lsum[qg];
        s += __shfl_xor(s, 16, 64);
        s += __shfl_xor(s, 32, 64);
        float inv = 8.0f / s;    // sqrt(HEAD_DIM) = 8
#pragma unroll
        for (int r = 0; r < 4; r++) {
            float iv = __shfl(inv, quad * 4 + r, 64);
            float* po = out + (size_t)(b0 + w * 32 + qg * 16 + quad * 4 + r) * 1024 + h * 64;
#pragma unroll
            for (int n = 0; n < 4; n++)
                po[n * 16 + l15] = accO[qg][n][r] * iv;
        }
    }
}

// ---------------------------------------------------------------------------
extern "C" void kernel_launch(void* const* d_in, const int* in_sizes, int n_in,
                              void* d_out, int out_size, void* d_ws, size_t ws_size,
                              hipStream_t stream) {
    (void)in_sizes; (void)n_in; (void)out_size; (void)ws_size;
    const float* x   = (const float*)d_in[0];
    const float* Wq  = (const float*)d_in[1];
    const float* mem = (const float*)d_in[2];
    float* out = (float*)d_out;

    unsigned short* qn = (unsigned short*)d_ws;                 // 8 MB
    unsigned short* F  = qn + (size_t)B_SZ * 1024;              // 16 MB (frag-ordered)
    unsigned short* xh = F  + (size_t)HEADS * 64 * 16 * 512;    // 8 MB
    unsigned short* Wh = xh + (size_t)B_SZ * K_IN;              // 2 MB   (total 34 MB)

    k_conv    <<<2560, 256, 0, stream>>>(x, Wq, xh, Wh);
    k_prep_mem<<<dim3(64, 16), 256, 0, stream>>>(mem, F);
    k_qproj   <<<dim3(32, 16), 256, 0, stream>>>(xh, Wh, qn);
    k_attn    <<<512, 256, 0, stream>>>(qn, F, out);
}

// Round 5
// 176.538 us; speedup vs baseline: 1.1927x; 1.0219x over previous
//
#include <hip/hip_runtime.h>
#include <stdint.h>

#define B_SZ  4096
#define HEADS 16
#define HD    64
#define M_SZ  4096
#define K_IN  1024
#define SW    72    // padded LDS row stride (f16 elems)
#define LOG2E 1.44269504088896f

typedef _Float16 f16;
typedef f16  f16x4 __attribute__((ext_vector_type(4)));
typedef f16  f16x8 __attribute__((ext_vector_type(8)));
typedef float f32x4 __attribute__((ext_vector_type(4)));

union U8 { uint4 u4; f16x8 h8; unsigned int ui[4]; unsigned short us[8]; };

__device__ __forceinline__ unsigned short f2h(float f) {
    _Float16 h = (_Float16)f;
    return __builtin_bit_cast(unsigned short, h);
}
__device__ __forceinline__ f16x8 ldsv8(const unsigned short* p) {
    U8 u; u.u4 = *reinterpret_cast<const uint4*>(p); return u.h8;
}
__device__ __forceinline__ f16x8 gldv8(const unsigned short* p) {
    U8 u; u.u4 = *reinterpret_cast<const uint4*>(p); return u.h8;
}

#if __has_builtin(__builtin_amdgcn_exp2f)
#define EXP2F(x) __builtin_amdgcn_exp2f(x)
#else
#define EXP2F(x) __expf((x) * 0.6931471805599453f)
#endif

// async global -> LDS: lane i's 16 B land at ldsbase + i*16
__device__ __forceinline__ void gload_lds16(const void* g, void* l) {
    __builtin_amdgcn_global_load_lds(
        (const __attribute__((address_space(1))) void*)g,
        (__attribute__((address_space(3))) void*)l, 16, 0, 0);
}

// ---------------------------------------------------------------------------
// Kernel 0: f32 -> f16 conversion of x and Wq (one pass).  [round-0 verbatim]
// ---------------------------------------------------------------------------
__global__ __launch_bounds__(256) void k_conv(const float* __restrict__ x,
                                              const float* __restrict__ Wq,
                                              unsigned short* __restrict__ xh,
                                              unsigned short* __restrict__ Wh) {
    const int b = blockIdx.x;
    const float* src;
    unsigned short* dst;
    size_t base;
    if (b < 2048) { src = x;  dst = xh; base = (size_t)b * 2048; }
    else          { src = Wq; dst = Wh; base = (size_t)(b - 2048) * 2048; }
    const size_t i = base + (size_t)threadIdx.x * 8;
    float4 f0 = reinterpret_cast<const float4*>(src + i)[0];
    float4 f1 = reinterpret_cast<const float4*>(src + i)[1];
    U8 u;
    u.us[0] = f2h(f0.x); u.us[1] = f2h(f0.y); u.us[2] = f2h(f0.z); u.us[3] = f2h(f0.w);
    u.us[4] = f2h(f1.x); u.us[5] = f2h(f1.y); u.us[6] = f2h(f1.z); u.us[7] = f2h(f1.w);
    *reinterpret_cast<uint4*>(dst + i) = u.u4;
}

// ---------------------------------------------------------------------------
// Kernel 1: normalize memories, emit fragment-ordered F[h][tile64][chunk16][lane][8]
// chunks 0..7  (gs=g*2+s): QK A-frag (16x16x32), PERMUTED m:
//   elem = Mn[m_phys(g, lane&15)][d = s*32 + (lane>>4)*8 + j]
//   m_phys(g,r) = 32*(g>>1) + (r>>2)*8 + 4*(g&1) + (r&3)
// chunks 8..15 (c2=p*4+n): PV B-frag (16x16x32), physical m:
//   elem = Mn[32*p + (lane>>4)*8 + j][d = n*16 + (lane&15)]
// After QK+exp, lane's regs {g=2p,r0..3; g=2p+1,r0..3} are exactly the PV A-frag.
// [round-0 verbatim]
// ---------------------------------------------------------------------------
__global__ __launch_bounds__(256) void k_prep_mem(const float* __restrict__ mem,
                                                  unsigned short* __restrict__ F) {
    __shared__ float part[64][4];
    __shared__ float scale[64];
    __shared__ unsigned short Tn[64 * SW];

    const int h  = blockIdx.y;
    const int tl = blockIdx.x;
    const int m0 = tl * 64;
    const int tid = threadIdx.x;
    const int r = tid >> 2;
    const int c = tid & 3;

    const float* src = mem + ((size_t)(h * M_SZ + m0 + r)) * HD + c * 16;
    float v[16];
    float ss = 0.f;
#pragma unroll
    for (int i = 0; i < 4; i++) {
        float4 f = reinterpret_cast<const float4*>(src)[i];
        v[4*i+0] = f.x; v[4*i+1] = f.y; v[4*i+2] = f.z; v[4*i+3] = f.w;
        ss += f.x*f.x + f.y*f.y + f.z*f.z + f.w*f.w;
    }
    part[r][c] = ss;
    __syncthreads();
    if (tid < 64) {
        float s = part[tid][0] + part[tid][1] + part[tid][2] + part[tid][3];
        scale[tid] = rsqrtf(s);
    }
    __syncthreads();
    const float sc = scale[r];

    U8 a, b;
#pragma unroll
    for (int i = 0; i < 8; i++) { a.us[i] = f2h(v[i] * sc); b.us[i] = f2h(v[8 + i] * sc); }
    *reinterpret_cast<uint4*>(&Tn[r * SW + c * 16])     = a.u4;
    *reinterpret_cast<uint4*>(&Tn[r * SW + c * 16 + 8]) = b.u4;
    __syncthreads();

    const int w = tid >> 6, lane = tid & 63;
    const int l15 = lane & 15, quad = lane >> 4;
    unsigned short* Fd = F + ((size_t)(h * 64 + tl) * 16) * 512;

    // QK A-frag chunks (permuted m)
#pragma unroll
    for (int i = 0; i < 2; i++) {
        const int ch = w * 2 + i, g = ch >> 1, s = ch & 1;
        const int mp = 32 * (g >> 1) + ((l15 >> 2) * 8) + 4 * (g & 1) + (l15 & 3);
        uint4 vv = *reinterpret_cast<const uint4*>(&Tn[mp * SW + s * 32 + quad * 8]);
        *reinterpret_cast<uint4*>(Fd + ch * 512 + lane * 8) = vv;
    }
    // PV B-frag chunks (physical m)
#pragma unroll
    for (int i = 0; i < 2; i++) {
        const int c2 = w * 2 + i, p = c2 >> 2, n = c2 & 3;
        U8 u;
#pragma unroll
        for (int j = 0; j < 8; j++)
            u.us[j] = Tn[(32 * p + quad * 8 + j) * SW + n * 16 + l15];
        *reinterpret_cast<uint4*>(Fd + (8 + c2) * 512 + lane * 8) = u.u4;
    }
}

// ---------------------------------------------------------------------------
// Kernel 2: q = xh @ Wh^T (f16 MFMA, 128x64 tile = one head), fused L2 norm,
// prescaled by log2(e). grid (32, 16) = 512 blocks -> 2 blocks/CU. [verbatim]
// ---------------------------------------------------------------------------
__global__ __launch_bounds__(256, 2) void k_qproj(const unsigned short* __restrict__ xh,
                                                  const unsigned short* __restrict__ Wh,
                                                  unsigned short* __restrict__ qn) {
    __shared__ unsigned short As[128 * SW];
    __shared__ unsigned short Bs[64 * SW];

    const int b0 = blockIdx.x * 128;
    const int n0 = blockIdx.y * 64;     // == h*64
    const int t = threadIdx.x;
    const int w = t >> 6, lane = t & 63;
    const int l15 = lane & 15, quad = lane >> 4;

    f32x4 acc[2][4] = {};

    for (int kb = 0; kb < K_IN; kb += 64) {
        __syncthreads();
        {
            const unsigned short* px = xh + (size_t)(b0 + (t >> 1)) * K_IN + kb + (t & 1) * 32;
            const unsigned short* pw = Wh + (size_t)(n0 + (t >> 2)) * K_IN + kb + (t & 3) * 16;
            uint4 av[4];
#pragma unroll
            for (int i = 0; i < 4; i++) av[i] = reinterpret_cast<const uint4*>(px)[i];
            uint4 bv[2];
#pragma unroll
            for (int i = 0; i < 2; i++) bv[i] = reinterpret_cast<const uint4*>(pw)[i];
#pragma unroll
            for (int i = 0; i < 4; i++)
                *reinterpret_cast<uint4*>(&As[(t >> 1) * SW + (t & 1) * 32 + i * 8]) = av[i];
#pragma unroll
            for (int i = 0; i < 2; i++)
                *reinterpret_cast<uint4*>(&Bs[(t >> 2) * SW + (t & 3) * 16 + i * 8]) = bv[i];
        }
        __syncthreads();

#pragma unroll
        for (int s = 0; s < 2; s++) {
            f16x8 af[2];
#pragma unroll
            for (int qg = 0; qg < 2; qg++)
                af[qg] = ldsv8(&As[(w * 32 + qg * 16 + l15) * SW + s * 32 + quad * 8]);
#pragma unroll
            for (int g = 0; g < 4; g++) {
                f16x8 bf_ = ldsv8(&Bs[(g * 16 + l15) * SW + s * 32 + quad * 8]);
#pragma unroll
                for (int qg = 0; qg < 2; qg++)
                    acc[qg][g] = __builtin_amdgcn_mfma_f32_16x16x32_f16(af[qg], bf_, acc[qg][g], 0, 0, 0);
            }
        }
    }

    __syncthreads();
    unsigned short* Ct = As;   // 128 x SW
#pragma unroll
    for (int qg = 0; qg < 2; qg++) {
        float ssq[4];
#pragma unroll
        for (int r = 0; r < 4; r++) {
            float s = 0.f;
#pragma unroll
            for (int g = 0; g < 4; g++) s += acc[qg][g][r] * acc[qg][g][r];
            ssq[r] = s;
        }
#pragma unroll
        for (int mask = 1; mask <= 8; mask <<= 1)
#pragma unroll
            for (int r = 0; r < 4; r++) ssq[r] += __shfl_xor(ssq[r], mask, 64);
#pragma unroll
        for (int r = 0; r < 4; r++) {
            float inv = rsqrtf(ssq[r]) * LOG2E;
#pragma unroll
            for (int g = 0; g < 4; g++)
                Ct[(w * 32 + qg * 16 + quad * 4 + r) * SW + g * 16 + l15] = f2h(acc[qg][g][r] * inv);
        }
    }
    __syncthreads();

    const int row = t >> 1, half = (t & 1) * 32;
    unsigned short* dq = qn + (size_t)(b0 + row) * 1024 + n0 + half;
#pragma unroll
    for (int i = 0; i < 4; i++)
        reinterpret_cast<uint4*>(dq)[i] = *reinterpret_cast<const uint4*>(&Ct[row * SW + half + i * 8]);
}

// ---------------------------------------------------------------------------
// Kernel 3: fused attention v6 — r4 structure with RELAXED SYNC WINDOWS.
// 8 LDS buffers (64 KB), staging pushed to tile tl+5, barrier once per 4
// tiles (17 total vs 64): waves drift up to ~4 tiles, letting MFMA and VALU
// phases of different waves overlap instead of barrier-convoying.
// Overwrite safety (NB=8 >= 2W=8): buffer (tl+5)&7 last held tile tl-3,
// read in body(tl-4), sealed by the previous window barrier.
// V-frags stay global->VGPR; QK A-frags via LDS. Persistent zero C-operand.
// ---------------------------------------------------------------------------
__global__ __launch_bounds__(256, 2) void k_attn(const unsigned short* __restrict__ qn,
                                                 const unsigned short* __restrict__ F,
                                                 float* __restrict__ out) {
    __shared__ unsigned short buf[8][4096];   // 8 x 8 KB (QK chunks only)

    const int b = blockIdx.x;
    const int h  = 2 * (b & 7) + (b >> 8);    // XCD k serves heads {2k, 2k+1}
    const int b0 = ((b >> 3) & 31) * 128;
    const int t = threadIdx.x;
    const int w = t >> 6, lane = t & 63;
    const int l15 = lane & 15, quad = lane >> 4;

    const f32x4 Z = {0.f, 0.f, 0.f, 0.f};     // persistent MFMA C=0 operand

    // Q as B-operand of 16x16x32: lane holds Q[q=l15][d = s*32 + quad*8 + j]
    f16x8 qf[2][2];
#pragma unroll
    for (int qg = 0; qg < 2; qg++)
#pragma unroll
        for (int s = 0; s < 2; s++) {
            U8 u;
            u.u4 = *reinterpret_cast<const uint4*>(
                qn + (size_t)(b0 + w * 32 + qg * 16 + l15) * 1024 + h * 64 + s * 32 + quad * 8);
            qf[qg][s] = u.h8;
        }

    const unsigned short* Fh = F + (size_t)h * 64 * 8192;

    f32x4 accO[2][4] = {};
    float lsum[2] = {0.f, 0.f};

    // pipeline register state (double-buffered)
    f16x8 puA[2][2], puB[2][2];   // P A-frags [qg][p]
    f16x8 bwA[8],   bwB[8];       // V B-frags [p*4+n]  (filled from GLOBAL)

    // ---- prologue ----
    // stage tile 0 QK chunks
#pragma unroll
    for (int i = 0; i < 2; i++) {
        const int ch = w * 2 + i;
        gload_lds16(Fh + ch * 512 + lane * 8, &buf[0][ch * 512]);
    }
    __syncthreads();
    {
        f16x8 am[8];
#pragma unroll
        for (int ch = 0; ch < 8; ch++) am[ch] = ldsv8(&buf[0][ch * 512 + lane * 8]);
#pragma unroll
        for (int ch = 0; ch < 8; ch++) bwA[ch] = gldv8(Fh + (8 + ch) * 512 + lane * 8);
        // stage tiles 1..4 (covered by the first window barrier)
#pragma unroll
        for (int tp = 1; tp <= 4; tp++) {
#pragma unroll
            for (int i = 0; i < 2; i++) {
                const int ch = w * 2 + i;
                gload_lds16(Fh + (size_t)tp * 8192 + ch * 512 + lane * 8, &buf[tp][ch * 512]);
            }
        }
#pragma unroll
        for (int g = 0; g < 4; g++) {
            const int qg = g >> 1, p = g & 1;
            f32x4 t0 = __builtin_amdgcn_mfma_f32_16x16x32_f16(am[4*p+0], qf[qg][0], Z, 0, 0, 0);
            t0 = __builtin_amdgcn_mfma_f32_16x16x32_f16(am[4*p+1], qf[qg][1], t0, 0, 0, 0);
            f32x4 t1 = __builtin_amdgcn_mfma_f32_16x16x32_f16(am[4*p+2], qf[qg][0], Z, 0, 0, 0);
            t1 = __builtin_amdgcn_mfma_f32_16x16x32_f16(am[4*p+3], qf[qg][1], t1, 0, 0, 0);
            float p0 = EXP2F(t0[0]), p1 = EXP2F(t0[1]), p2 = EXP2F(t0[2]), p3 = EXP2F(t0[3]);
            float p4 = EXP2F(t1[0]), p5 = EXP2F(t1[1]), p6 = EXP2F(t1[2]), p7 = EXP2F(t1[3]);
            lsum[qg] += ((p0 + p1) + (p2 + p3)) + ((p4 + p5) + (p6 + p7));
            U8 pu;
#if __has_builtin(__builtin_amdgcn_cvt_pkrtz)
            pu.ui[0] = __builtin_bit_cast(unsigned int, __builtin_amdgcn_cvt_pkrtz(p0, p1));
            pu.ui[1] = __builtin_bit_cast(unsigned int, __builtin_amdgcn_cvt_pkrtz(p2, p3));
            pu.ui[2] = __builtin_bit_cast(unsigned int, __builtin_amdgcn_cvt_pkrtz(p4, p5));
            pu.ui[3] = __builtin_bit_cast(unsigned int, __builtin_amdgcn_cvt_pkrtz(p6, p7));
#else
            pu.us[0]=f2h(p0); pu.us[1]=f2h(p1); pu.us[2]=f2h(p2); pu.us[3]=f2h(p3);
            pu.us[4]=f2h(p4); pu.us[5]=f2h(p5); pu.us[6]=f2h(p6); pu.us[7]=f2h(p7);
#endif
            puA[qg][p] = pu.h8;
        }
    }

    // ---- pipelined body: PV(tl) || QK(tl+1); NO internal barrier ----
    auto body = [&](int tl, f16x8 (&puC)[2][2], f16x8 (&bwC)[8],
                            f16x8 (&puN)[2][2], f16x8 (&bwN)[8]) {
        const unsigned short* lb = buf[(tl + 1) & 7];
        f16x8 amn[8];
#pragma unroll
        for (int ch = 0; ch < 8; ch++) amn[ch] = ldsv8(&lb[ch * 512 + lane * 8]);
        // V(tl+1) global->reg: used one body later; L2 latency hidden
        const unsigned short* gv = Fh + (size_t)(tl + 1) * 8192;
#pragma unroll
        for (int ch = 0; ch < 8; ch++) bwN[ch] = gldv8(gv + (8 + ch) * 512 + lane * 8);
        if (tl + 5 < 64) {   // stage tile tl+5 QK chunks into buf[(tl+5)&7]
            const unsigned short* gsrc = Fh + (size_t)(tl + 5) * 8192;
#pragma unroll
            for (int i = 0; i < 2; i++) {
                const int ch = w * 2 + i;
                gload_lds16(gsrc + ch * 512 + lane * 8, &buf[(tl + 5) & 7][ch * 512]);
            }
        }

        f32x4 sa[4], sb[4];
        auto expPack = [&](int g) {
            const int qg = g >> 1, p = g & 1;
            float p0 = EXP2F(sa[g][0]), p1 = EXP2F(sa[g][1]), p2 = EXP2F(sa[g][2]), p3 = EXP2F(sa[g][3]);
            float p4 = EXP2F(sb[g][0]), p5 = EXP2F(sb[g][1]), p6 = EXP2F(sb[g][2]), p7 = EXP2F(sb[g][3]);
            lsum[qg] += ((p0 + p1) + (p2 + p3)) + ((p4 + p5) + (p6 + p7));
            U8 pu;
#if __has_builtin(__builtin_amdgcn_cvt_pkrtz)
            pu.ui[0] = __builtin_bit_cast(unsigned int, __builtin_amdgcn_cvt_pkrtz(p0, p1));
            pu.ui[1] = __builtin_bit_cast(unsigned int, __builtin_amdgcn_cvt_pkrtz(p2, p3));
            pu.ui[2] = __builtin_bit_cast(unsigned int, __builtin_amdgcn_cvt_pkrtz(p4, p5));
            pu.ui[3] = __builtin_bit_cast(unsigned int, __builtin_amdgcn_cvt_pkrtz(p6, p7));
#else
            pu.us[0]=f2h(p0); pu.us[1]=f2h(p1); pu.us[2]=f2h(p2); pu.us[3]=f2h(p3);
            pu.us[4]=f2h(p4); pu.us[5]=f2h(p5); pu.us[6]=f2h(p6); pu.us[7]=f2h(p7);
#endif
            puN[qg][p] = pu.h8;
        };

#pragma unroll
        for (int g = 0; g < 4; g++) {
            const int qg = g >> 1, p = g & 1;
            // QK group g of tile tl+1
            f32x4 t0 = __builtin_amdgcn_mfma_f32_16x16x32_f16(amn[4*p+0], qf[qg][0], Z, 0, 0, 0);
            t0 = __builtin_amdgcn_mfma_f32_16x16x32_f16(amn[4*p+1], qf[qg][1], t0, 0, 0, 0);
            f32x4 t1 = __builtin_amdgcn_mfma_f32_16x16x32_f16(amn[4*p+2], qf[qg][0], Z, 0, 0, 0);
            t1 = __builtin_amdgcn_mfma_f32_16x16x32_f16(amn[4*p+3], qf[qg][1], t1, 0, 0, 0);
            sa[g] = t0; sb[g] = t1;
            // PV group g of tile tl (independent of the QK above)
#pragma unroll
            for (int n = 0; n < 4; n++)
                accO[qg][n] = __builtin_amdgcn_mfma_f32_16x16x32_f16(puC[qg][p], bwC[p * 4 + n], accO[qg][n], 0, 0, 0);
            // exp of the PREVIOUS group (its QK results are long since ready)
            if (g >= 1) expPack(g - 1);
        }
        expPack(3);
    };

    // windows of 4 tiles: barrier at tt even (tl = 4k), 17 barriers total
    for (int tt = 0; tt < 31; ++tt) {
        if ((tt & 1) == 0) __syncthreads();
        body(2 * tt,     puA, bwA, puB, bwB);
        body(2 * tt + 1, puB, bwB, puA, bwA);
    }
    body(62, puA, bwA, puB, bwB);

    // ---- epilogue: PV(63) from register set B, then normalize + store ----
#pragma unroll
    for (int g = 0; g < 4; g++) {
        const int qg = g >> 1, p = g & 1;
#pragma unroll
        for (int n = 0; n < 4; n++)
            accO[qg][n] = __builtin_amdgcn_mfma_f32_16x16x32_f16(puB[qg][p], bwB[p * 4 + n], accO[qg][n], 0, 0, 0);
    }

#pragma unroll
    for (int qg = 0; qg < 2; qg++) {
        float s = lsum[qg];
        s += __shfl_xor(s, 16, 64);
        s += __shfl_xor(s, 32, 64);
        float inv = 8.0f / s;    // sqrt(HEAD_DIM) = 8
#pragma unroll
        for (int r = 0; r < 4; r++) {
            float iv = __shfl(inv, quad * 4 + r, 64);
            float* po = out + (size_t)(b0 + w * 32 + qg * 16 + quad * 4 + r) * 1024 + h * 64;
#pragma unroll
            for (int n = 0; n < 4; n++)
                po[n * 16 + l15] = accO[qg][n][r] * iv;
        }
    }
}

// ---------------------------------------------------------------------------
extern "C" void kernel_launch(void* const* d_in, const int* in_sizes, int n_in,
                              void* d_out, int out_size, void* d_ws, size_t ws_size,
                              hipStream_t stream) {
    (void)in_sizes; (void)n_in; (void)out_size; (void)ws_size;
    const float* x   = (const float*)d_in[0];
    const float* Wq  = (const float*)d_in[1];
    const float* mem = (const float*)d_in[2];
    float* out = (float*)d_out;

    unsigned short* qn = (unsigned short*)d_ws;                 // 8 MB
    unsigned short* F  = qn + (size_t)B_SZ * 1024;              // 16 MB (frag-ordered)
    unsigned short* xh = F  + (size_t)HEADS * 64 * 16 * 512;    // 8 MB
    unsigned short* Wh = xh + (size_t)B_SZ * K_IN;              // 2 MB   (total 34 MB)

    k_conv    <<<2560, 256, 0, stream>>>(x, Wq, xh, Wh);
    k_prep_mem<<<dim3(64, 16), 256, 0, stream>>>(mem, F);
    k_qproj   <<<dim3(32, 16), 256, 0, stream>>>(xh, Wh, qn);
    k_attn    <<<512, 256, 0, stream>>>(qn, F, out);
}

// Round 7
// 175.321 us; speedup vs baseline: 1.2010x; 1.0069x over previous
//
#include <hip/hip_runtime.h>
#include <stdint.h>

#define B_SZ  4096
#define HEADS 16
#define HD    64
#define M_SZ  4096
#define K_IN  1024
#define SW    72    // padded LDS row stride (f16 elems)
#define LOG2E 1.44269504088896f

typedef _Float16 f16;
typedef f16  f16x2 __attribute__((ext_vector_type(2)));
typedef f16  f16x4 __attribute__((ext_vector_type(4)));
typedef f16  f16x8 __attribute__((ext_vector_type(8)));
typedef float f32x4 __attribute__((ext_vector_type(4)));

union U8 { uint4 u4; f16x8 h8; unsigned int ui[4]; unsigned short us[8]; };

__device__ __forceinline__ unsigned short f2h(float f) {
    _Float16 h = (_Float16)f;
    return __builtin_bit_cast(unsigned short, h);
}
__device__ __forceinline__ f16x8 ldsv8(const unsigned short* p) {
    U8 u; u.u4 = *reinterpret_cast<const uint4*>(p); return u.h8;
}

#if __has_builtin(__builtin_amdgcn_exp2f)
#define EXP2F(x) __builtin_amdgcn_exp2f(x)
#else
#define EXP2F(x) __expf((x) * 0.6931471805599453f)
#endif

// async global -> LDS: lane i's 16 B land at ldsbase + i*16
__device__ __forceinline__ void gload_lds16(const void* g, void* l) {
    __builtin_amdgcn_global_load_lds(
        (const __attribute__((address_space(1))) void*)g,
        (__attribute__((address_space(3))) void*)l, 16, 0, 0);
}

// ---------------------------------------------------------------------------
// Kernel 0: f32 -> f16 conversion of x and Wq (one pass).  [round-0 verbatim]
// ---------------------------------------------------------------------------
__global__ __launch_bounds__(256) void k_conv(const float* __restrict__ x,
                                              const float* __restrict__ Wq,
                                              unsigned short* __restrict__ xh,
                                              unsigned short* __restrict__ Wh) {
    const int b = blockIdx.x;
    const float* src;
    unsigned short* dst;
    size_t base;
    if (b < 2048) { src = x;  dst = xh; base = (size_t)b * 2048; }
    else          { src = Wq; dst = Wh; base = (size_t)(b - 2048) * 2048; }
    const size_t i = base + (size_t)threadIdx.x * 8;
    float4 f0 = reinterpret_cast<const float4*>(src + i)[0];
    float4 f1 = reinterpret_cast<const float4*>(src + i)[1];
    U8 u;
    u.us[0] = f2h(f0.x); u.us[1] = f2h(f0.y); u.us[2] = f2h(f0.z); u.us[3] = f2h(f0.w);
    u.us[4] = f2h(f1.x); u.us[5] = f2h(f1.y); u.us[6] = f2h(f1.z); u.us[7] = f2h(f1.w);
    *reinterpret_cast<uint4*>(dst + i) = u.u4;
}

// ---------------------------------------------------------------------------
// Kernel 1: normalize memories, emit fragment-ordered F[h][tile64][chunk16][lane][8]
// chunks 0..7  (gs=g*2+s): QK A-frag (16x16x32), PERMUTED m:
//   elem = Mn[m_phys(g, lane&15)][d = s*32 + (lane>>4)*8 + j]
//   m_phys(g,r) = 32*(g>>1) + (r>>2)*8 + 4*(g&1) + (r&3)
// chunks 8..15 (c2=p*4+n): PV B-frag (16x16x32), physical m:
//   elem = Mn[32*p + (lane>>4)*8 + j][d = n*16 + (lane&15)]
// After QK+exp, lane's regs {g=2p,r0..3; g=2p+1,r0..3} are exactly the PV A-frag.
// [round-0 verbatim]
// ---------------------------------------------------------------------------
__global__ __launch_bounds__(256) void k_prep_mem(const float* __restrict__ mem,
                                                  unsigned short* __restrict__ F) {
    __shared__ float part[64][4];
    __shared__ float scale[64];
    __shared__ unsigned short Tn[64 * SW];

    const int h  = blockIdx.y;
    const int tl = blockIdx.x;
    const int m0 = tl * 64;
    const int tid = threadIdx.x;
    const int r = tid >> 2;
    const int c = tid & 3;

    const float* src = mem + ((size_t)(h * M_SZ + m0 + r)) * HD + c * 16;
    float v[16];
    float ss = 0.f;
#pragma unroll
    for (int i = 0; i < 4; i++) {
        float4 f = reinterpret_cast<const float4*>(src)[i];
        v[4*i+0] = f.x; v[4*i+1] = f.y; v[4*i+2] = f.z; v[4*i+3] = f.w;
        ss += f.x*f.x + f.y*f.y + f.z*f.z + f.w*f.w;
    }
    part[r][c] = ss;
    __syncthreads();
    if (tid < 64) {
        float s = part[tid][0] + part[tid][1] + part[tid][2] + part[tid][3];
        scale[tid] = rsqrtf(s);
    }
    __syncthreads();
    const float sc = scale[r];

    U8 a, b;
#pragma unroll
    for (int i = 0; i < 8; i++) { a.us[i] = f2h(v[i] * sc); b.us[i] = f2h(v[8 + i] * sc); }
    *reinterpret_cast<uint4*>(&Tn[r * SW + c * 16])     = a.u4;
    *reinterpret_cast<uint4*>(&Tn[r * SW + c * 16 + 8]) = b.u4;
    __syncthreads();

    const int w = tid >> 6, lane = tid & 63;
    const int l15 = lane & 15, quad = lane >> 4;
    unsigned short* Fd = F + ((size_t)(h * 64 + tl) * 16) * 512;

    // QK A-frag chunks (permuted m)
#pragma unroll
    for (int i = 0; i < 2; i++) {
        const int ch = w * 2 + i, g = ch >> 1, s = ch & 1;
        const int mp = 32 * (g >> 1) + ((l15 >> 2) * 8) + 4 * (g & 1) + (l15 & 3);
        uint4 vv = *reinterpret_cast<const uint4*>(&Tn[mp * SW + s * 32 + quad * 8]);
        *reinterpret_cast<uint4*>(Fd + ch * 512 + lane * 8) = vv;
    }
    // PV B-frag chunks (physical m)
#pragma unroll
    for (int i = 0; i < 2; i++) {
        const int c2 = w * 2 + i, p = c2 >> 2, n = c2 & 3;
        U8 u;
#pragma unroll
        for (int j = 0; j < 8; j++)
            u.us[j] = Tn[(32 * p + quad * 8 + j) * SW + n * 16 + l15];
        *reinterpret_cast<uint4*>(Fd + (8 + c2) * 512 + lane * 8) = u.u4;
    }
}

// ---------------------------------------------------------------------------
// Kernel 2: q = xh @ Wh^T (f16 MFMA, 128x64 tile = one head), fused L2 norm,
// prescaled by log2(e). grid (32, 16) = 512 blocks -> 2 blocks/CU. [verbatim]
// ---------------------------------------------------------------------------
__global__ __launch_bounds__(256, 2) void k_qproj(const unsigned short* __restrict__ xh,
                                                  const unsigned short* __restrict__ Wh,
                                                  unsigned short* __restrict__ qn) {
    __shared__ unsigned short As[128 * SW];
    __shared__ unsigned short Bs[64 * SW];

    const int b0 = blockIdx.x * 128;
    const int n0 = blockIdx.y * 64;     // == h*64
    const int t = threadIdx.x;
    const int w = t >> 6, lane = t & 63;
    const int l15 = lane & 15, quad = lane >> 4;

    f32x4 acc[2][4] = {};

    for (int kb = 0; kb < K_IN; kb += 64) {
        __syncthreads();
        {
            const unsigned short* px = xh + (size_t)(b0 + (t >> 1)) * K_IN + kb + (t & 1) * 32;
            const unsigned short* pw = Wh + (size_t)(n0 + (t >> 2)) * K_IN + kb + (t & 3) * 16;
            uint4 av[4];
#pragma unroll
            for (int i = 0; i < 4; i++) av[i] = reinterpret_cast<const uint4*>(px)[i];
            uint4 bv[2];
#pragma unroll
            for (int i = 0; i < 2; i++) bv[i] = reinterpret_cast<const uint4*>(pw)[i];
#pragma unroll
            for (int i = 0; i < 4; i++)
                *reinterpret_cast<uint4*>(&As[(t >> 1) * SW + (t & 1) * 32 + i * 8]) = av[i];
#pragma unroll
            for (int i = 0; i < 2; i++)
                *reinterpret_cast<uint4*>(&Bs[(t >> 2) * SW + (t & 3) * 16 + i * 8]) = bv[i];
        }
        __syncthreads();

#pragma unroll
        for (int s = 0; s < 2; s++) {
            f16x8 af[2];
#pragma unroll
            for (int qg = 0; qg < 2; qg++)
                af[qg] = ldsv8(&As[(w * 32 + qg * 16 + l15) * SW + s * 32 + quad * 8]);
#pragma unroll
            for (int g = 0; g < 4; g++) {
                f16x8 bf_ = ldsv8(&Bs[(g * 16 + l15) * SW + s * 32 + quad * 8]);
#pragma unroll
                for (int qg = 0; qg < 2; qg++)
                    acc[qg][g] = __builtin_amdgcn_mfma_f32_16x16x32_f16(af[qg], bf_, acc[qg][g], 0, 0, 0);
            }
        }
    }

    __syncthreads();
    unsigned short* Ct = As;   // 128 x SW
#pragma unroll
    for (int qg = 0; qg < 2; qg++) {
        float ssq[4];
#pragma unroll
        for (int r = 0; r < 4; r++) {
            float s = 0.f;
#pragma unroll
            for (int g = 0; g < 4; g++) s += acc[qg][g][r] * acc[qg][g][r];
            ssq[r] = s;
        }
#pragma unroll
        for (int mask = 1; mask <= 8; mask <<= 1)
#pragma unroll
            for (int r = 0; r < 4; r++) ssq[r] += __shfl_xor(ssq[r], mask, 64);
#pragma unroll
        for (int r = 0; r < 4; r++) {
            float inv = rsqrtf(ssq[r]) * LOG2E;
#pragma unroll
            for (int g = 0; g < 4; g++)
                Ct[(w * 32 + qg * 16 + quad * 4 + r) * SW + g * 16 + l15] = f2h(acc[qg][g][r] * inv);
        }
    }
    __syncthreads();

    const int row = t >> 1, half = (t & 1) * 32;
    unsigned short* dq = qn + (size_t)(b0 + row) * 1024 + n0 + half;
#pragma unroll
    for (int i = 0; i < 4; i++)
        reinterpret_cast<uint4*>(dq)[i] = *reinterpret_cast<const uint4*>(&Ct[row * SW + half + i * 8]);
}

// ---------------------------------------------------------------------------
// Kernel 3: fused attention v7 — round-0 memory scheme (V in LDS, full 16 KB
// tiles, best measured 77.4 µs) + three stacked refinements:
//  (1) 4-buffer window sync: stage tl+3, barrier per 2 tiles (33 vs 64).
//      Safety: buffer (tl+3)&3 last read two bodies back, sealed by the
//      intervening window barrier; reads sealed by barrier after staging.
//  (2) s_setprio(1) around each 8-MFMA cluster (T5): 2 waves/SIMD are from
//      different blocks (independent barriers) -> scheduler can antiphase
//      one wave's MFMA against the other's exp.
//  (3) lsum via v_dot2_f32_f16(pu, 1): shorter serial chain than 7-add tree.
// ---------------------------------------------------------------------------
__global__ __launch_bounds__(256, 2) void k_attn(const unsigned short* __restrict__ qn,
                                                 const unsigned short* __restrict__ F,
                                                 float* __restrict__ out) {
    __shared__ unsigned short buf[4][8192];   // 4 x 16 KB

    const int b = blockIdx.x;
    const int h  = 2 * (b & 7) + (b >> 8);    // XCD k serves heads {2k, 2k+1}
    const int b0 = ((b >> 3) & 31) * 128;
    const int t = threadIdx.x;
    const int w = t >> 6, lane = t & 63;
    const int l15 = lane & 15, quad = lane >> 4;

    const f32x4 Z = {0.f, 0.f, 0.f, 0.f};

    // Q as B-operand of 16x16x32: lane holds Q[q=l15][d = s*32 + quad*8 + j]
    f16x8 qf[2][2];
#pragma unroll
    for (int qg = 0; qg < 2; qg++)
#pragma unroll
        for (int s = 0; s < 2; s++) {
            U8 u;
            u.u4 = *reinterpret_cast<const uint4*>(
                qn + (size_t)(b0 + w * 32 + qg * 16 + l15) * 1024 + h * 64 + s * 32 + quad * 8);
            qf[qg][s] = u.h8;
        }

    const unsigned short* Fh = F + (size_t)h * 64 * 8192;

    f32x4 accO[2][4] = {};
    float lsum[2] = {0.f, 0.f};

    // pipeline register state (double-buffered)
    f16x8 puA[2][2], puB[2][2];   // P A-frags [qg][p]
    f16x8 bwA[8],   bwB[8];       // V B-frags [p*4+n]

#if __has_builtin(__builtin_amdgcn_fdot2)
    const f16x2 one2 = {(_Float16)1.f, (_Float16)1.f};
#define LSUM4(qgi, puv)                                                          \
    {                                                                            \
        float s_ = lsum[qgi];                                                    \
        s_ = __builtin_amdgcn_fdot2(__builtin_bit_cast(f16x2, (puv).ui[0]), one2, s_, false); \
        s_ = __builtin_amdgcn_fdot2(__builtin_bit_cast(f16x2, (puv).ui[1]), one2, s_, false); \
        s_ = __builtin_amdgcn_fdot2(__builtin_bit_cast(f16x2, (puv).ui[2]), one2, s_, false); \
        s_ = __builtin_amdgcn_fdot2(__builtin_bit_cast(f16x2, (puv).ui[3]), one2, s_, false); \
        lsum[qgi] = s_;                                                          \
    }
#else
#define LSUM4(qgi, puv)                                                          \
    {                                                                            \
        float a0 = (float)(puv).h8[0] + (float)(puv).h8[1];                      \
        float a1 = (float)(puv).h8[2] + (float)(puv).h8[3];                      \
        float a2 = (float)(puv).h8[4] + (float)(puv).h8[5];                      \
        float a3 = (float)(puv).h8[6] + (float)(puv).h8[7];                      \
        lsum[qgi] += (a0 + a1) + (a2 + a3);                                      \
    }
#endif

    // ---- prologue: stage tiles 0..2, compute pu(0)/bw(0) into set A ----
#pragma unroll
    for (int tp = 0; tp < 3; tp++)
#pragma unroll
        for (int i = 0; i < 4; i++) {
            const int ch = w * 4 + i;
            gload_lds16(Fh + (size_t)tp * 8192 + ch * 512 + lane * 8, &buf[tp][ch * 512]);
        }
    __syncthreads();
    {
        f16x8 am[8];
#pragma unroll
        for (int ch = 0; ch < 8; ch++) am[ch] = ldsv8(&buf[0][ch * 512 + lane * 8]);
#pragma unroll
        for (int ch = 0; ch < 8; ch++) bwA[ch] = ldsv8(&buf[0][(8 + ch) * 512 + lane * 8]);
#pragma unroll
        for (int g = 0; g < 4; g++) {
            const int qg = g >> 1, p = g & 1;
            f32x4 t0 = __builtin_amdgcn_mfma_f32_16x16x32_f16(am[4*p+0], qf[qg][0], Z, 0, 0, 0);
            t0 = __builtin_amdgcn_mfma_f32_16x16x32_f16(am[4*p+1], qf[qg][1], t0, 0, 0, 0);
            f32x4 t1 = __builtin_amdgcn_mfma_f32_16x16x32_f16(am[4*p+2], qf[qg][0], Z, 0, 0, 0);
            t1 = __builtin_amdgcn_mfma_f32_16x16x32_f16(am[4*p+3], qf[qg][1], t1, 0, 0, 0);
            float p0 = EXP2F(t0[0]), p1 = EXP2F(t0[1]), p2 = EXP2F(t0[2]), p3 = EXP2F(t0[3]);
            float p4 = EXP2F(t1[0]), p5 = EXP2F(t1[1]), p6 = EXP2F(t1[2]), p7 = EXP2F(t1[3]);
            U8 pu;
#if __has_builtin(__builtin_amdgcn_cvt_pkrtz)
            pu.ui[0] = __builtin_bit_cast(unsigned int, __builtin_amdgcn_cvt_pkrtz(p0, p1));
            pu.ui[1] = __builtin_bit_cast(unsigned int, __builtin_amdgcn_cvt_pkrtz(p2, p3));
            pu.ui[2] = __builtin_bit_cast(unsigned int, __builtin_amdgcn_cvt_pkrtz(p4, p5));
            pu.ui[3] = __builtin_bit_cast(unsigned int, __builtin_amdgcn_cvt_pkrtz(p6, p7));
#else
            pu.us[0]=f2h(p0); pu.us[1]=f2h(p1); pu.us[2]=f2h(p2); pu.us[3]=f2h(p3);
            pu.us[4]=f2h(p4); pu.us[5]=f2h(p5); pu.us[6]=f2h(p6); pu.us[7]=f2h(p7);
#endif
            LSUM4(qg, pu);
            puA[qg][p] = pu.h8;
        }
    }

    // ---- pipelined body: PV(tl) || QK(tl+1); barrier hoisted to window ----
    auto body = [&](int tl, f16x8 (&puC)[2][2], f16x8 (&bwC)[8],
                            f16x8 (&puN)[2][2], f16x8 (&bwN)[8]) {
        const unsigned short* lb = buf[(tl + 1) & 3];
        f16x8 amn[8];
#pragma unroll
        for (int ch = 0; ch < 8; ch++) amn[ch] = ldsv8(&lb[ch * 512 + lane * 8]);
#pragma unroll
        for (int ch = 0; ch < 8; ch++) bwN[ch] = ldsv8(&lb[(8 + ch) * 512 + lane * 8]);
        if (tl + 3 < 64) {   // stage tile tl+3 into buf[(tl+3)&3]
            const unsigned short* gsrc = Fh + (size_t)(tl + 3) * 8192;
#pragma unroll
            for (int i = 0; i < 4; i++) {
                const int ch = w * 4 + i;
                gload_lds16(gsrc + ch * 512 + lane * 8, &buf[(tl + 3) & 3][ch * 512]);
            }
        }

        f32x4 sa[4], sb[4];
        auto expPack = [&](int g) {
            const int qg = g >> 1, p = g & 1;
            float p0 = EXP2F(sa[g][0]), p1 = EXP2F(sa[g][1]), p2 = EXP2F(sa[g][2]), p3 = EXP2F(sa[g][3]);
            float p4 = EXP2F(sb[g][0]), p5 = EXP2F(sb[g][1]), p6 = EXP2F(sb[g][2]), p7 = EXP2F(sb[g][3]);
            U8 pu;
#if __has_builtin(__builtin_amdgcn_cvt_pkrtz)
            pu.ui[0] = __builtin_bit_cast(unsigned int, __builtin_amdgcn_cvt_pkrtz(p0, p1));
            pu.ui[1] = __builtin_bit_cast(unsigned int, __builtin_amdgcn_cvt_pkrtz(p2, p3));
            pu.ui[2] = __builtin_bit_cast(unsigned int, __builtin_amdgcn_cvt_pkrtz(p4, p5));
            pu.ui[3] = __builtin_bit_cast(unsigned int, __builtin_amdgcn_cvt_pkrtz(p6, p7));
#else
            pu.us[0]=f2h(p0); pu.us[1]=f2h(p1); pu.us[2]=f2h(p2); pu.us[3]=f2h(p3);
            pu.us[4]=f2h(p4); pu.us[5]=f2h(p5); pu.us[6]=f2h(p6); pu.us[7]=f2h(p7);
#endif
            LSUM4(qg, pu);
            puN[qg][p] = pu.h8;
        };

#pragma unroll
        for (int g = 0; g < 4; g++) {
            const int qg = g >> 1, p = g & 1;
            __builtin_amdgcn_s_setprio(1);
            // QK group g of tile tl+1
            f32x4 t0 = __builtin_amdgcn_mfma_f32_16x16x32_f16(amn[4*p+0], qf[qg][0], Z, 0, 0, 0);
            t0 = __builtin_amdgcn_mfma_f32_16x16x32_f16(amn[4*p+1], qf[qg][1], t0, 0, 0, 0);
            f32x4 t1 = __builtin_amdgcn_mfma_f32_16x16x32_f16(amn[4*p+2], qf[qg][0], Z, 0, 0, 0);
            t1 = __builtin_amdgcn_mfma_f32_16x16x32_f16(amn[4*p+3], qf[qg][1], t1, 0, 0, 0);
            sa[g] = t0; sb[g] = t1;
            // PV group g of tile tl (independent of the QK above)
#pragma unroll
            for (int n = 0; n < 4; n++)
                accO[qg][n] = __builtin_amdgcn_mfma_f32_16x16x32_f16(puC[qg][p], bwC[p * 4 + n], accO[qg][n], 0, 0, 0);
            __builtin_amdgcn_s_setprio(0);
            // exp of the PREVIOUS group (its QK results are long since ready)
            if (g >= 1) expPack(g - 1);
        }
        expPack(3);
    };

    // windows of 2 tiles: barrier at even tl (0,2,...,62) -> 32 in-loop syncs
    for (int tt = 0; tt < 31; ++tt) {
        __syncthreads();
        body(2 * tt,     puA, bwA, puB, bwB);
        body(2 * tt + 1, puB, bwB, puA, bwA);
    }
    __syncthreads();
    body(62, puA, bwA, puB, bwB);

    // ---- epilogue: PV(63) from register set B, then normalize + store ----
#pragma unroll
    for (int g = 0; g < 4; g++) {
        const int qg = g >> 1, p = g & 1;
#pragma unroll
        for (int n = 0; n < 4; n++)
            accO[qg][n] = __builtin_amdgcn_mfma_f32_16x16x32_f16(puB[qg][p], bwB[p * 4 + n], accO[qg][n], 0, 0, 0);
    }

#pragma unroll
    for (int qg = 0; qg < 2; qg++) {
        float s = lsum[qg];
        s += __shfl_xor(s, 16, 64);
        s += __shfl_xor(s, 32, 64);
        float inv = 8.0f / s;    // sqrt(HEAD_DIM) = 8
#pragma unroll
        for (int r = 0; r < 4; r++) {
            float iv = __shfl(inv, quad * 4 + r, 64);
            float* po = out + (size_t)(b0 + w * 32 + qg * 16 + quad * 4 + r) * 1024 + h * 64;
#pragma unroll
            for (int n = 0; n < 4; n++)
                po[n * 16 + l15] = accO[qg][n][r] * iv;
        }
    }
}

// ---------------------------------------------------------------------------
extern "C" void kernel_launch(void* const* d_in, const int* in_sizes, int n_in,
                              void* d_out, int out_size, void* d_ws, size_t ws_size,
                              hipStream_t stream) {
    (void)in_sizes; (void)n_in; (void)out_size; (void)ws_size;
    const float* x   = (const float*)d_in[0];
    const float* Wq  = (const float*)d_in[1];
    const float* mem = (const float*)d_in[2];
    float* out = (float*)d_out;

    unsigned short* qn = (unsigned short*)d_ws;                 // 8 MB
    unsigned short* F  = qn + (size_t)B_SZ * 1024;              // 16 MB (frag-ordered)
    unsigned short* xh = F  + (size_t)HEADS * 64 * 16 * 512;    // 8 MB
    unsigned short* Wh = xh + (size_t)B_SZ * K_IN;              // 2 MB   (total 34 MB)

    k_conv    <<<2560, 256, 0, stream>>>(x, Wq, xh, Wh);
    k_prep_mem<<<dim3(64, 16), 256, 0, stream>>>(mem, F);
    k_qproj   <<<dim3(32, 16), 256, 0, stream>>>(xh, Wh, qn);
    k_attn    <<<512, 256, 0, stream>>>(qn, F, out);
}